// Round 1
// baseline (686.925 us; speedup 1.0000x reference)
//
#include <hip/hip_runtime.h>
#include <math.h>

// Problem constants
// B=1, N=256, H=32, W=32, M=1024, C_LIDAR=C_RGB=64, K=16, S=3, MLP3=[128,64,64]

// ---------------- workspace layout (float offsets) ----------------
constexpr int WS_XYZ  = 0;                  // 256*3
constexpr int WS_RF   = 768;                // 1024*64
constexpr int WS_RFI  = WS_RF   + 65536;    // 1024*3
constexpr int WS_SN   = WS_RFI  + 3072;     // 256*64   l2norm(warped_points)
constexpr int WS_DN   = WS_SN   + 16384;    // 1024*64  l2norm(rf)
constexpr int WS_SIM1 = WS_DN   + 65536;    // 1024*256 sim[m][n]
constexpr int WS_RM1  = WS_SIM1 + 262144;   // 1024 max over n
constexpr int WS_CM1  = WS_RM1  + 1024;     // 256  max over m
constexpr int WS_PCF  = WS_CM1  + 256;      // 256*64
constexpr int WS_IMGF = WS_PCF  + 16384;    // 1024*64
constexpr int WS_PCN  = WS_IMGF + 65536;    // 256*64
constexpr int WS_IMGN = WS_PCN  + 16384;    // 1024*64
constexpr int WS_SIM2 = WS_IMGN + 65536;    // 1024*256
constexpr int WS_RM2  = WS_SIM2 + 262144;   // 1024
constexpr int WS_CM2  = WS_RM2  + 1024;     // 256
constexpr int WS_B1   = WS_CM2  + 256;      // 256*128  n-only part of MLP1 layer1 (incl bias)
constexpr int WS_B2   = WS_B1   + 32768;    // 1024*128 m-only part of MLP1 layer1
constexpr int WS_ATT  = WS_B2   + 131072;   // 256*64
constexpr int WS_UV   = WS_ATT  + 16384;    // 256*3
constexpr int WS_WIN  = WS_UV   + 768;      // 256
constexpr int WS_KNN  = WS_WIN  + 256;      // 256*16 ints
// total: 1027328 floats ~= 4.11 MB

// ---------------- prep: xyz, rf, rfi transposes ----------------
__global__ __launch_bounds__(256) void prep_kernel(float* ws, const float* wxyz,
                                                   const float* lz, const float* RF3,
                                                   const float* RFI) {
    int i = blockIdx.x * 256 + threadIdx.x;
    if (i < 768) {
        int n = i / 3;
        ws[WS_XYZ + i] = wxyz[i] * lz[n];
    } else if (i < 768 + 65536) {
        int j = i - 768; int mm = j >> 6, c = j & 63;
        ws[WS_RF + j] = RF3[c * 1024 + mm];
    } else if (i < 768 + 65536 + 3072) {
        int j = i - (768 + 65536); int mm = j / 3, c = j - mm * 3;
        ws[WS_RFI + j] = RFI[c * 1024 + mm];
    }
}

// ---------------- row L2-normalize (64 cols) ----------------
__global__ __launch_bounds__(64) void rownorm_kernel(const float* src, float* dst) {
    int r = blockIdx.x, t = threadIdx.x;
    float v = src[r * 64 + t];
    float s = v * v;
    for (int o = 32; o > 0; o >>= 1) s += __shfl_down(s, o);
    s = __shfl(s, 0);
    float nrm = sqrtf(s);
    dst[r * 64 + t] = v / fmaxf(nrm, 1e-12f);
}

// ---------------- sim[m][n] = d[m] . s[n]; rowmax over n ----------------
__global__ __launch_bounds__(256) void sim_kernel(const float* dn, const float* sn,
                                                  float* sim, float* rmax) {
    __shared__ __align__(16) float dv[64];
    __shared__ float red[256];
    int m = blockIdx.x, t = threadIdx.x;
    if (t < 64) dv[t] = dn[m * 64 + t];
    __syncthreads();
    float acc = 0.f;
    const float4* sp = (const float4*)(sn + t * 64);
    const float4* dp = (const float4*)dv;
    for (int i = 0; i < 16; i++) {
        float4 s4 = sp[i], d4 = dp[i];
        acc += s4.x * d4.x + s4.y * d4.y + s4.z * d4.z + s4.w * d4.w;
    }
    sim[m * 256 + t] = acc;
    red[t] = acc; __syncthreads();
    for (int s = 128; s > 0; s >>= 1) {
        if (t < s) red[t] = fmaxf(red[t], red[t + s]);
        __syncthreads();
    }
    if (t == 0) rmax[m] = red[0];
}

// ---------------- colmax over m per n ----------------
__global__ __launch_bounds__(256) void colmax_kernel(const float* sim, float* cmax) {
    __shared__ float red[256];
    int n = blockIdx.x, t = threadIdx.x;
    float mx = -INFINITY;
    for (int m = t; m < 1024; m += 256) mx = fmaxf(mx, sim[m * 256 + n]);
    red[t] = mx; __syncthreads();
    for (int s = 128; s > 0; s >>= 1) {
        if (t < s) red[t] = fmaxf(red[t], red[t + s]);
        __syncthreads();
    }
    if (t == 0) cmax[n] = red[0];
}

// ---------------- 16-NN per point ----------------
__global__ __launch_bounds__(256) void knn_kernel(float* ws) {
    const float* xyz = ws + WS_XYZ;
    int* knn = (int*)(ws + WS_KNN);
    __shared__ float px[256], py[256], pz[256], d2[256];
    __shared__ float rv[256];
    __shared__ int   ri[256];
    int n = blockIdx.x, t = threadIdx.x;
    px[t] = xyz[t * 3 + 0]; py[t] = xyz[t * 3 + 1]; pz[t] = xyz[t * 3 + 2];
    __syncthreads();
    float dx = px[t] - px[n], dy = py[t] - py[n], dz = pz[t] - pz[n];
    d2[t] = dx * dx + dy * dy + dz * dz;
    __syncthreads();
    for (int k = 0; k < 16; k++) {
        rv[t] = d2[t]; ri[t] = t;
        __syncthreads();
        for (int s = 128; s > 0; s >>= 1) {
            if (t < s) {
                float v2 = rv[t + s]; int i2 = ri[t + s];
                if (v2 < rv[t] || (v2 == rv[t] && i2 < ri[t])) { rv[t] = v2; ri[t] = i2; }
            }
            __syncthreads();
        }
        if (t == 0) { knn[n * 16 + k] = ri[0]; d2[ri[0]] = INFINITY; }
        __syncthreads();
    }
}

// ---------------- point branch: MLP2 over 16 neighbors -> pc_feats ----------------
__global__ __launch_bounds__(256) void mlp2_kernel(float* ws, const float* wpts,
        const float* w0, const float* b0, const float* w1, const float* b1,
        const float* w2, const float* b2) {
    __shared__ float wA[68 * 64], wB[64 * 64], wC[64 * 64];
    __shared__ float bA[64], bB[64], bC[64];
    __shared__ float x[16 * 68], hA[16 * 68], hB[16 * 68];
    __shared__ int   kn[16];
    __shared__ float wv[16], wts[16];
    int n = blockIdx.x, t = threadIdx.x;
    const float* xyz = ws + WS_XYZ;
    const int* knn = (const int*)(ws + WS_KNN);
    for (int i = t; i < 68 * 64; i += 256) wA[i] = w0[i];
    for (int i = t; i < 64 * 64; i += 256) { wB[i] = w1[i]; wC[i] = w2[i]; }
    if (t < 64) { bA[t] = b0[t]; bB[t] = b1[t]; bC[t] = b2[t]; }
    if (t < 16) kn[t] = knn[n * 16 + t];
    __syncthreads();
    for (int i = t; i < 1024; i += 256) {
        int k = i >> 6, c = i & 63;
        x[k * 68 + c] = wpts[kn[k] * 64 + c];
    }
    if (t < 16) {
        int i = kn[t];
        float dx = xyz[i * 3 + 0] - xyz[n * 3 + 0];
        float dy = xyz[i * 3 + 1] - xyz[n * 3 + 1];
        float dz = xyz[i * 3 + 2] - xyz[n * 3 + 2];
        x[t * 68 + 64] = dx; x[t * 68 + 65] = dy; x[t * 68 + 66] = dz;
        x[t * 68 + 67] = sqrtf(dx * dx + dy * dy + dz * dz);
    }
    __syncthreads();
    for (int o = t; o < 1024; o += 256) {
        int k = o >> 6, j = o & 63; float acc = bA[j];
        for (int i = 0; i < 68; i++) acc += x[k * 68 + i] * wA[i * 64 + j];
        hA[k * 68 + j] = fmaxf(acc, 0.f);
    }
    __syncthreads();
    for (int o = t; o < 1024; o += 256) {
        int k = o >> 6, j = o & 63; float acc = bB[j];
        for (int i = 0; i < 64; i++) acc += hA[k * 68 + i] * wB[i * 64 + j];
        hB[k * 68 + j] = fmaxf(acc, 0.f);
    }
    __syncthreads();
    for (int o = t; o < 1024; o += 256) {
        int k = o >> 6, j = o & 63; float acc = bC[j];
        for (int i = 0; i < 64; i++) acc += hB[k * 68 + i] * wC[i * 64 + j];
        hA[k * 68 + j] = fmaxf(acc, 0.f);   // h3 overwrites h1 buffer
    }
    __syncthreads();
    if (t < 16) {
        float mx = -INFINITY;
        for (int j = 0; j < 64; j++) mx = fmaxf(mx, hA[t * 68 + j]);
        wv[t] = mx;
    }
    __syncthreads();
    if (t < 16) {
        float mx = -INFINITY;
        for (int k = 0; k < 16; k++) mx = fmaxf(mx, wv[k]);
        float sum = 0.f;
        for (int k = 0; k < 16; k++) sum += expf(wv[k] - mx);
        wts[t] = expf(wv[t] - mx) / sum;
    }
    __syncthreads();
    if (t < 64) {
        float acc = 0.f;
        for (int k = 0; k < 16; k++) acc += wts[k] * x[k * 68 + t];
        ws[WS_PCF + n * 64 + t] = acc;
    }
}

// ---------------- image branch: MLP3 over 3x3 window -> img_feats ----------------
__global__ __launch_bounds__(256) void mlp3_kernel(float* ws,
        const float* w0, const float* b0, const float* w1, const float* b1,
        const float* w2, const float* b2) {
    __shared__ float wA[67 * 64], wB[64 * 64], wC[64 * 64];
    __shared__ float bA[64], bB[64], bC[64];
    __shared__ float x[9 * 68], hA[9 * 68], hB[9 * 68];
    __shared__ float wv[9], iw[9];
    int m = blockIdx.x, t = threadIdx.x;
    int y = m >> 5, xx = m & 31;
    const float* rf = ws + WS_RF;
    const float* rfi = ws + WS_RFI;
    for (int i = t; i < 67 * 64; i += 256) wA[i] = w0[i];
    for (int i = t; i < 64 * 64; i += 256) { wB[i] = w1[i]; wC[i] = w2[i]; }
    if (t < 64) { bA[t] = b0[t]; bB[t] = b1[t]; bC[t] = b2[t]; }
    if (t < 27) {
        int kk = t / 3, c = t - kk * 3;
        int dy = kk / 3 - 1, dxo = kk % 3 - 1;
        int ny = y + dy, nx = xx + dxo;
        bool val = (ny >= 0 && ny < 32 && nx >= 0 && nx < 32);
        int m2 = ny * 32 + nx;
        x[kk * 68 + c] = val ? rfi[m2 * 3 + c] : 0.f;
    }
    __syncthreads();
    for (int i = t; i < 576; i += 256) {
        int kk = i >> 6, c = i & 63;
        int dy = kk / 3 - 1, dxo = kk % 3 - 1;
        int ny = y + dy, nx = xx + dxo;
        bool val = (ny >= 0 && ny < 32 && nx >= 0 && nx < 32);
        int m2 = ny * 32 + nx;
        x[kk * 68 + 3 + c] = val ? rf[m2 * 64 + c] : 0.f;
    }
    __syncthreads();
    for (int o = t; o < 576; o += 256) {
        int k = o >> 6, j = o & 63; float acc = bA[j];
        for (int i = 0; i < 67; i++) acc += x[k * 68 + i] * wA[i * 64 + j];
        hA[k * 68 + j] = fmaxf(acc, 0.f);
    }
    __syncthreads();
    for (int o = t; o < 576; o += 256) {
        int k = o >> 6, j = o & 63; float acc = bB[j];
        for (int i = 0; i < 64; i++) acc += hA[k * 68 + i] * wB[i * 64 + j];
        hB[k * 68 + j] = fmaxf(acc, 0.f);
    }
    __syncthreads();
    for (int o = t; o < 576; o += 256) {
        int k = o >> 6, j = o & 63; float acc = bC[j];
        for (int i = 0; i < 64; i++) acc += hB[k * 68 + i] * wC[i * 64 + j];
        hA[k * 68 + j] = fmaxf(acc, 0.f);
    }
    __syncthreads();
    if (t < 9) {
        float mx = -INFINITY;
        for (int j = 0; j < 64; j++) mx = fmaxf(mx, hA[t * 68 + j]);
        wv[t] = mx;
    }
    __syncthreads();
    if (t < 9) {
        float mx = -INFINITY;
        for (int k = 0; k < 9; k++) mx = fmaxf(mx, wv[k]);
        float sum = 0.f;
        for (int k = 0; k < 9; k++) sum += expf(wv[k] - mx);
        iw[t] = expf(wv[t] - mx) / sum;
    }
    __syncthreads();
    if (t < 64) {
        float acc = 0.f;
        for (int k = 0; k < 9; k++) acc += iw[k] * x[k * 68 + 3 + t];
        ws[WS_IMGF + m * 64 + t] = acc;
    }
}

// ---------------- MLP1 layer-1 decomposition ----------------
__global__ __launch_bounds__(128) void base1_kernel(float* ws, const float* wpts,
                                                    const float* w10, const float* b10) {
    int n = blockIdx.x, j = threadIdx.x;
    float acc = b10[j];
    for (int i = 0; i < 3; i++)  acc += ws[WS_XYZ + n * 3 + i] * w10[i * 128 + j];
    for (int c = 0; c < 64; c++) acc += wpts[n * 64 + c] * w10[(6 + c) * 128 + j];
    ws[WS_B1 + n * 128 + j] = acc;
}
__global__ __launch_bounds__(128) void base2_kernel(float* ws, const float* w10) {
    int m = blockIdx.x, j = threadIdx.x;
    float acc = 0.f;
    for (int i = 0; i < 3; i++)  acc += ws[WS_RFI + m * 3 + i] * w10[(3 + i) * 128 + j];
    for (int c = 0; c < 64; c++) acc += ws[WS_RF + m * 64 + c] * w10[(70 + c) * 128 + j];
    ws[WS_B2 + m * 128 + j] = acc;
}

// ---------------- main fused MLP1 + online softmax -> att, uv1 ----------------
__global__ __launch_bounds__(256) void mlp1_kernel(float* ws, const float* w10,
        const float* w11, const float* b11, const float* w12, const float* b12) {
    __shared__ __align__(16) float H1t[128 * 34];   // [k][row], pad stride 34
    __shared__ __align__(16) float H2t[64 * 34];
    __shared__ __align__(16) float H3[32 * 68];     // [row][col]
    __shared__ float base1n[128];
    __shared__ float simf[32 * 4];
    __shared__ float rfi3[32 * 3];
    __shared__ float rm[32], ew[32];
    int n = blockIdx.x, t = threadIdx.x;
    const float* sim1 = ws + WS_SIM1;  const float* rm1g = ws + WS_RM1;
    const float* sim2 = ws + WS_SIM2;  const float* rm2g = ws + WS_RM2;
    const float* base2 = ws + WS_B2;   const float* rfig = ws + WS_RFI;
    float cm1 = ws[WS_CM1 + n], cm2 = ws[WS_CM2 + n];
    if (t < 128) base1n[t] = ws[WS_B1 + n * 128 + t];
    int rg = t >> 4, cg = t & 15;
    float4 bias2 = *(const float4*)&b11[cg * 4];
    float4 bias3 = *(const float4*)&b12[cg * 4];
    float attAcc = 0.f, uvAcc = 0.f;
    float Mv = -INFINITY, Sv = 0.f;
    __syncthreads();
    for (int m0 = 0; m0 < 1024; m0 += 32) {
        if (t < 32) {
            int m = m0 + t;
            float s1 = sim1[m * 256 + n], r1 = rm1g[m];
            float s2 = sim2[m * 256 + n], r2 = rm2g[m];
            simf[t * 4 + 0] = s1 / (cm1 + 1e-6f);
            simf[t * 4 + 1] = s1 / (r1 + 1e-10f);
            simf[t * 4 + 2] = s2 / (cm2 + 1e-6f);
            simf[t * 4 + 3] = s2 / (r2 + 1e-10f);
        } else if (t >= 64 && t < 160) {
            int i = t - 64; int row = i / 3, c = i - row * 3;
            rfi3[i] = rfig[(m0 + row) * 3 + c];
        }
        __syncthreads();
        // layer 1 combine: H1t[k][row]
        for (int idx = t; idx < 4096; idx += 256) {
            int k = idx & 127, row = idx >> 7;
            int m = m0 + row;
            float v = base1n[k] + base2[m * 128 + k]
                    + simf[row * 4 + 0] * w10[134 * 128 + k]
                    + simf[row * 4 + 1] * w10[135 * 128 + k]
                    + simf[row * 4 + 2] * w10[136 * 128 + k]
                    + simf[row * 4 + 3] * w10[137 * 128 + k];
            H1t[k * 34 + row] = fmaxf(v, 0.f);
        }
        __syncthreads();
        // layer 2: 32 rows x 64 cols, thread tile 2x4
        {
            float a00 = bias2.x, a01 = bias2.y, a02 = bias2.z, a03 = bias2.w;
            float a10 = bias2.x, a11 = bias2.y, a12 = bias2.z, a13 = bias2.w;
            for (int k = 0; k < 128; k++) {
                float2 av = *(const float2*)&H1t[k * 34 + rg * 2];
                float4 bv = *(const float4*)&w11[k * 64 + cg * 4];
                a00 += av.x * bv.x; a01 += av.x * bv.y; a02 += av.x * bv.z; a03 += av.x * bv.w;
                a10 += av.y * bv.x; a11 += av.y * bv.y; a12 += av.y * bv.z; a13 += av.y * bv.w;
            }
            *(float2*)&H2t[(cg * 4 + 0) * 34 + rg * 2] = make_float2(fmaxf(a00, 0.f), fmaxf(a10, 0.f));
            *(float2*)&H2t[(cg * 4 + 1) * 34 + rg * 2] = make_float2(fmaxf(a01, 0.f), fmaxf(a11, 0.f));
            *(float2*)&H2t[(cg * 4 + 2) * 34 + rg * 2] = make_float2(fmaxf(a02, 0.f), fmaxf(a12, 0.f));
            *(float2*)&H2t[(cg * 4 + 3) * 34 + rg * 2] = make_float2(fmaxf(a03, 0.f), fmaxf(a13, 0.f));
        }
        __syncthreads();
        // layer 3
        {
            float c00 = bias3.x, c01 = bias3.y, c02 = bias3.z, c03 = bias3.w;
            float c10 = bias3.x, c11 = bias3.y, c12 = bias3.z, c13 = bias3.w;
            for (int k = 0; k < 64; k++) {
                float2 av = *(const float2*)&H2t[k * 34 + rg * 2];
                float4 bv = *(const float4*)&w12[k * 64 + cg * 4];
                c00 += av.x * bv.x; c01 += av.x * bv.y; c02 += av.x * bv.z; c03 += av.x * bv.w;
                c10 += av.y * bv.x; c11 += av.y * bv.y; c12 += av.y * bv.z; c13 += av.y * bv.w;
            }
            *(float4*)&H3[(rg * 2 + 0) * 68 + cg * 4] =
                make_float4(fmaxf(c00, 0.f), fmaxf(c01, 0.f), fmaxf(c02, 0.f), fmaxf(c03, 0.f));
            *(float4*)&H3[(rg * 2 + 1) * 68 + cg * 4] =
                make_float4(fmaxf(c10, 0.f), fmaxf(c11, 0.f), fmaxf(c12, 0.f), fmaxf(c13, 0.f));
        }
        __syncthreads();
        if (t < 32) {
            float mx = -INFINITY;
            for (int c = 0; c < 64; c++) mx = fmaxf(mx, H3[t * 68 + c]);
            rm[t] = mx;
        }
        __syncthreads();
        float tmax = -INFINITY;
        for (int r = 0; r < 32; r++) tmax = fmaxf(tmax, rm[r]);
        float newM = fmaxf(Mv, tmax);
        float rescale = expf(Mv - newM);
        if (t < 32) ew[t] = expf(rm[t] - newM);
        Mv = newM;
        __syncthreads();
        float sumew = 0.f;
        for (int r = 0; r < 32; r++) sumew += ew[r];
        Sv = Sv * rescale + sumew;
        if (t < 64) {
            float acc = 0.f;
            for (int r = 0; r < 32; r++) acc += ew[r] * H3[r * 68 + t];
            attAcc = attAcc * rescale + acc;
        } else if (t < 67) {
            int c = t - 64; float acc = 0.f;
            for (int r = 0; r < 32; r++) acc += ew[r] * rfi3[r * 3 + c];
            uvAcc = uvAcc * rescale + acc;
        }
        __syncthreads();
    }
    if (t < 64) ws[WS_ATT + n * 64 + t] = attAcc / Sv;
    else if (t < 67) ws[WS_UV + n * 3 + (t - 64)] = uvAcc / Sv;
}

// ---------------- head MLP -> weights (d_out), w_in ----------------
__global__ __launch_bounds__(128) void head_kernel(float* ws,
        const float* wm0, const float* bm0, const float* wm1, const float* bm1,
        const float* wm2, const float* bm2, float* out) {
    __shared__ float av[64], ha[64], hb[128], lg[2];
    int n = blockIdx.x, t = threadIdx.x;
    if (t < 64) av[t] = ws[WS_ATT + n * 64 + t];
    __syncthreads();
    if (t < 64) {
        float acc = bm0[t];
        for (int i = 0; i < 64; i++) acc += av[i] * wm0[i * 64 + t];
        ha[t] = fmaxf(acc, 0.f);
    }
    __syncthreads();
    {
        float acc = bm1[t];
        for (int i = 0; i < 64; i++) acc += ha[i] * wm1[i * 128 + t];
        hb[t] = fmaxf(acc, 0.f);
    }
    __syncthreads();
    if (t < 2) {
        float acc = bm2[t];
        for (int i = 0; i < 128; i++) acc += hb[i] * wm2[i * 2 + t];
        lg[t] = acc;
    }
    __syncthreads();
    if (t == 0) {
        float l0 = lg[0], l1 = lg[1];
        float mx = fmaxf(l0, l1);
        float e0 = expf(l0 - mx), e1 = expf(l1 - mx);
        float s = e0 + e1;
        out[12 + n * 2 + 0] = e0 / s;
        out[12 + n * 2 + 1] = e1 / s;
        ws[WS_WIN + n] = (e1 > e0) ? 1.f : 0.f;
    }
}

// ---------------- weighted PnP (Kabsch with 3x3 SVD, double) ----------------
__device__ void compute_rt(const double Hm[9], const double sc[3], const double dc[3],
                           float* out) {
    double Hd[3][3] = {{Hm[0], Hm[1], Hm[2]}, {Hm[3], Hm[4], Hm[5]}, {Hm[6], Hm[7], Hm[8]}};
    double A[3][3], V[3][3] = {{1, 0, 0}, {0, 1, 0}, {0, 0, 1}};
    for (int i = 0; i < 3; i++)
        for (int j = 0; j < 3; j++) {
            double s = 0;
            for (int k = 0; k < 3; k++) s += Hd[k][i] * Hd[k][j];
            A[i][j] = s;
        }
    for (int sweep = 0; sweep < 50; sweep++) {
        double off = fabs(A[0][1]) + fabs(A[0][2]) + fabs(A[1][2]);
        if (off < 1e-28) break;
        const int PQ[3][2] = {{0, 1}, {0, 2}, {1, 2}};
        for (int pp = 0; pp < 3; pp++) {
            int p = PQ[pp][0], q = PQ[pp][1];
            double apq = A[p][q];
            if (fabs(apq) < 1e-300) continue;
            double tau = (A[q][q] - A[p][p]) / (2.0 * apq);
            double tt = (tau >= 0.0 ? 1.0 : -1.0) / (fabs(tau) + sqrt(1.0 + tau * tau));
            double c = 1.0 / sqrt(1.0 + tt * tt), s = tt * c;
            for (int k = 0; k < 3; k++) {
                double akp = A[k][p], akq = A[k][q];
                A[k][p] = c * akp - s * akq; A[k][q] = s * akp + c * akq;
            }
            for (int k = 0; k < 3; k++) {
                double apk = A[p][k], aqk = A[q][k];
                A[p][k] = c * apk - s * aqk; A[q][k] = s * apk + c * aqk;
            }
            for (int k = 0; k < 3; k++) {
                double vkp = V[k][p], vkq = V[k][q];
                V[k][p] = c * vkp - s * vkq; V[k][q] = s * vkp + c * vkq;
            }
        }
    }
    double lam[3] = {A[0][0], A[1][1], A[2][2]};
    int o0 = 0, o1 = 1, o2 = 2;
    if (lam[o0] < lam[o1]) { int tp = o0; o0 = o1; o1 = tp; }
    if (lam[o0] < lam[o2]) { int tp = o0; o0 = o2; o2 = tp; }
    if (lam[o1] < lam[o2]) { int tp = o1; o1 = o2; o2 = tp; }
    int ord[3] = {o0, o1, o2};
    double v[3][3], u[3][3], R[3][3];
    for (int k = 0; k < 3; k++)
        for (int i = 0; i < 3; i++) v[k][i] = V[i][ord[k]];
    double sv0 = sqrt(fmax(lam[o0], 0.0));
    if (!(sv0 > 1e-150)) {
        for (int i = 0; i < 3; i++)
            for (int j = 0; j < 3; j++) R[i][j] = (i == j) ? 1.0 : 0.0;
    } else {
        double nn[3];
        for (int k = 0; k < 3; k++) {
            for (int i = 0; i < 3; i++)
                u[k][i] = Hd[i][0] * v[k][0] + Hd[i][1] * v[k][1] + Hd[i][2] * v[k][2];
            nn[k] = sqrt(u[k][0] * u[k][0] + u[k][1] * u[k][1] + u[k][2] * u[k][2]);
        }
        for (int i = 0; i < 3; i++) u[0][i] /= nn[0];
        if (nn[1] > 1e-12 * nn[0]) {
            for (int i = 0; i < 3; i++) u[1][i] /= nn[1];
        } else {
            int e = (fabs(u[0][0]) <= fabs(u[0][1]) && fabs(u[0][0]) <= fabs(u[0][2])) ? 0
                    : ((fabs(u[0][1]) <= fabs(u[0][2])) ? 1 : 2);
            double ev[3] = {0, 0, 0}; ev[e] = 1.0;
            double d0 = ev[0] * u[0][0] + ev[1] * u[0][1] + ev[2] * u[0][2];
            double w1v[3], wn2 = 0;
            for (int i = 0; i < 3; i++) { w1v[i] = ev[i] - d0 * u[0][i]; wn2 += w1v[i] * w1v[i]; }
            wn2 = sqrt(wn2);
            for (int i = 0; i < 3; i++) u[1][i] = w1v[i] / wn2;
        }
        if (nn[2] > 1e-10 * nn[0]) {
            for (int i = 0; i < 3; i++) u[2][i] /= nn[2];
        } else {
            u[2][0] = u[0][1] * u[1][2] - u[0][2] * u[1][1];
            u[2][1] = u[0][2] * u[1][0] - u[0][0] * u[1][2];
            u[2][2] = u[0][0] * u[1][1] - u[0][1] * u[1][0];
        }
        double cr[3] = {u[1][1] * u[2][2] - u[1][2] * u[2][1],
                        u[1][2] * u[2][0] - u[1][0] * u[2][2],
                        u[1][0] * u[2][1] - u[1][1] * u[2][0]};
        double detU = u[0][0] * cr[0] + u[0][1] * cr[1] + u[0][2] * cr[2];
        double cv[3] = {v[1][1] * v[2][2] - v[1][2] * v[2][1],
                        v[1][2] * v[2][0] - v[1][0] * v[2][2],
                        v[1][0] * v[2][1] - v[1][1] * v[2][0]};
        double detV = v[0][0] * cv[0] + v[0][1] * cv[1] + v[0][2] * cv[2];
        double dsign = detU * detV;
        for (int i = 0; i < 3; i++)
            for (int j = 0; j < 3; j++)
                R[i][j] = v[0][i] * u[0][j] + v[1][i] * u[1][j] + dsign * v[2][i] * u[2][j];
    }
    for (int i = 0; i < 3; i++) {
        double ti = dc[i] - (R[i][0] * sc[0] + R[i][1] * sc[1] + R[i][2] * sc[2]);
        out[9 + i] = (float)ti;
        for (int j = 0; j < 3; j++) out[i * 3 + j] = (float)R[i][j];
    }
}

__global__ __launch_bounds__(256) void pnp_kernel(float* ws, float* out) {
    __shared__ double red[256];
    int t = threadIdx.x;
    double w = (double)ws[WS_WIN + t];
    double x0 = ws[WS_XYZ + t * 3 + 0];
    double x1 = ws[WS_XYZ + t * 3 + 1];
    double x2 = ws[WS_XYZ + t * 3 + 2];
    double z = x2;
    double dd0 = (double)ws[WS_UV + t * 3 + 0] * z;
    double dd1 = (double)ws[WS_UV + t * 3 + 1] * z;
    double dd2 = z;
    auto reduce = [&](double v) -> double {
        red[t] = v; __syncthreads();
        for (int s = 128; s > 0; s >>= 1) {
            if (t < s) red[t] += red[t + s];
            __syncthreads();
        }
        double r = red[0]; __syncthreads();
        return r;
    };
    double wsum = reduce(w);
    double sx0 = reduce(w * x0), sx1 = reduce(w * x1), sx2 = reduce(w * x2);
    double sd0 = reduce(w * dd0), sd1 = reduce(w * dd1), sd2 = reduce(w * dd2);
    double inv = 1.0 / (wsum + 1e-8);
    double sc[3] = {sx0 * inv, sx1 * inv, sx2 * inv};
    double dc[3] = {sd0 * inv, sd1 * inv, sd2 * inv};
    double wn = w * inv;
    double a0 = x0 - sc[0], a1 = x1 - sc[1], a2 = x2 - sc[2];
    double b0 = dd0 - dc[0], b1 = dd1 - dc[1], b2 = dd2 - dc[2];
    double Hm[9];
    Hm[0] = reduce(wn * a0 * b0); Hm[1] = reduce(wn * a0 * b1); Hm[2] = reduce(wn * a0 * b2);
    Hm[3] = reduce(wn * a1 * b0); Hm[4] = reduce(wn * a1 * b1); Hm[5] = reduce(wn * a1 * b2);
    Hm[6] = reduce(wn * a2 * b0); Hm[7] = reduce(wn * a2 * b1); Hm[8] = reduce(wn * a2 * b2);
    if (t == 0) compute_rt(Hm, sc, dc, out);
}

// ---------------- launch ----------------
extern "C" void kernel_launch(void* const* d_in, const int* in_sizes, int n_in,
                              void* d_out, int out_size, void* d_ws, size_t ws_size,
                              hipStream_t stream) {
    float* ws = (float*)d_ws;
    const float* wxyz = (const float*)d_in[0];
    const float* wpts = (const float*)d_in[1];
    const float* RF3  = (const float*)d_in[2];
    const float* RFI  = (const float*)d_in[3];
    const float* lz   = (const float*)d_in[4];
    const float* w2_0 = (const float*)d_in[5];  const float* b2_0 = (const float*)d_in[6];
    const float* w2_1 = (const float*)d_in[7];  const float* b2_1 = (const float*)d_in[8];
    const float* w2_2 = (const float*)d_in[9];  const float* b2_2 = (const float*)d_in[10];
    const float* w3_0 = (const float*)d_in[11]; const float* b3_0 = (const float*)d_in[12];
    const float* w3_1 = (const float*)d_in[13]; const float* b3_1 = (const float*)d_in[14];
    const float* w3_2 = (const float*)d_in[15]; const float* b3_2 = (const float*)d_in[16];
    const float* w1_0 = (const float*)d_in[17]; const float* b1_0 = (const float*)d_in[18];
    const float* w1_1 = (const float*)d_in[19]; const float* b1_1 = (const float*)d_in[20];
    const float* w1_2 = (const float*)d_in[21]; const float* b1_2 = (const float*)d_in[22];
    const float* wm_0 = (const float*)d_in[23]; const float* bm_0 = (const float*)d_in[24];
    const float* wm_1 = (const float*)d_in[25]; const float* bm_1 = (const float*)d_in[26];
    const float* wm_2 = (const float*)d_in[27]; const float* bm_2 = (const float*)d_in[28];
    float* out = (float*)d_out;

    prep_kernel<<<272, 256, 0, stream>>>(ws, wxyz, lz, RF3, RFI);
    rownorm_kernel<<<256, 64, 0, stream>>>(wpts, ws + WS_SN);
    rownorm_kernel<<<1024, 64, 0, stream>>>(ws + WS_RF, ws + WS_DN);
    sim_kernel<<<1024, 256, 0, stream>>>(ws + WS_DN, ws + WS_SN, ws + WS_SIM1, ws + WS_RM1);
    colmax_kernel<<<256, 256, 0, stream>>>(ws + WS_SIM1, ws + WS_CM1);
    knn_kernel<<<256, 256, 0, stream>>>(ws);
    mlp2_kernel<<<256, 256, 0, stream>>>(ws, wpts, w2_0, b2_0, w2_1, b2_1, w2_2, b2_2);
    mlp3_kernel<<<1024, 256, 0, stream>>>(ws, w3_0, b3_0, w3_1, b3_1, w3_2, b3_2);
    rownorm_kernel<<<256, 64, 0, stream>>>(ws + WS_PCF, ws + WS_PCN);
    rownorm_kernel<<<1024, 64, 0, stream>>>(ws + WS_IMGF, ws + WS_IMGN);
    sim_kernel<<<1024, 256, 0, stream>>>(ws + WS_IMGN, ws + WS_PCN, ws + WS_SIM2, ws + WS_RM2);
    colmax_kernel<<<256, 256, 0, stream>>>(ws + WS_SIM2, ws + WS_CM2);
    base1_kernel<<<256, 128, 0, stream>>>(ws, wpts, w1_0, b1_0);
    base2_kernel<<<1024, 128, 0, stream>>>(ws, w1_0);
    mlp1_kernel<<<256, 256, 0, stream>>>(ws, w1_0, w1_1, b1_1, w1_2, b1_2);
    head_kernel<<<256, 128, 0, stream>>>(ws, wm_0, bm_0, wm_1, bm_1, wm_2, bm_2, out);
    pnp_kernel<<<1, 256, 0, stream>>>(ws, out);
}

// Round 2
// 621.185 us; speedup vs baseline: 1.1058x; 1.1058x over previous
//
#include <hip/hip_runtime.h>
#include <math.h>

// Problem constants
// B=1, N=256, H=32, W=32, M=1024, C_LIDAR=C_RGB=64, K=16, S=3, MLP3=[128,64,64]

// ---------------- workspace layout (float offsets) ----------------
constexpr int WS_XYZ  = 0;                  // 256*3
constexpr int WS_RF   = 768;                // 1024*64
constexpr int WS_RFI  = WS_RF   + 65536;    // 1024*3
constexpr int WS_SN   = WS_RFI  + 3072;     // 256*64   l2norm(warped_points)
constexpr int WS_DN   = WS_SN   + 16384;    // 1024*64  l2norm(rf)
constexpr int WS_SIM1 = WS_DN   + 65536;    // 1024*256 sim[m][n]
constexpr int WS_RM1  = WS_SIM1 + 262144;   // 1024 max over n
constexpr int WS_CM1  = WS_RM1  + 1024;     // 256  max over m
constexpr int WS_PCF  = WS_CM1  + 256;      // 256*64
constexpr int WS_IMGF = WS_PCF  + 16384;    // 1024*64
constexpr int WS_PCN  = WS_IMGF + 65536;    // 256*64
constexpr int WS_IMGN = WS_PCN  + 16384;    // 1024*64
constexpr int WS_SIM2 = WS_IMGN + 65536;    // 1024*256
constexpr int WS_RM2  = WS_SIM2 + 262144;   // 1024
constexpr int WS_CM2  = WS_RM2  + 1024;     // 256
constexpr int WS_B1   = WS_CM2  + 256;      // 256*128  n-only part of MLP1 layer1 (incl bias)
constexpr int WS_B2   = WS_B1   + 32768;    // 1024*128 m-only part of MLP1 layer1
constexpr int WS_ATT  = WS_B2   + 131072;   // 256*64
constexpr int WS_UV   = WS_ATT  + 16384;    // 256*3
constexpr int WS_WIN  = WS_UV   + 768;      // 256
constexpr int WS_KNN  = WS_WIN  + 256;      // 256*16 ints
constexpr int WS_PM   = WS_KNN  + 4096;     // 256*4 partial max
constexpr int WS_PS   = WS_PM   + 1024;     // 256*4 partial sum
constexpr int WS_PATT = WS_PS   + 1024;     // 256*4*64 partial att
constexpr int WS_PUV  = WS_PATT + 65536;    // 256*4*3 partial uv
// total: 1097984 floats ~= 4.39 MB

// ---------------- prep: xyz, rf, rfi transposes ----------------
__global__ __launch_bounds__(256) void prep_kernel(float* ws, const float* wxyz,
                                                   const float* lz, const float* RF3,
                                                   const float* RFI) {
    int i = blockIdx.x * 256 + threadIdx.x;
    if (i < 768) {
        int n = i / 3;
        ws[WS_XYZ + i] = wxyz[i] * lz[n];
    } else if (i < 768 + 65536) {
        int j = i - 768; int mm = j >> 6, c = j & 63;
        ws[WS_RF + j] = RF3[c * 1024 + mm];
    } else if (i < 768 + 65536 + 3072) {
        int j = i - (768 + 65536); int mm = j / 3, c = j - mm * 3;
        ws[WS_RFI + j] = RFI[c * 1024 + mm];
    }
}

// ---------------- row L2-normalize (64 cols) ----------------
__global__ __launch_bounds__(64) void rownorm_kernel(const float* src, float* dst) {
    int r = blockIdx.x, t = threadIdx.x;
    float v = src[r * 64 + t];
    float s = v * v;
    for (int o = 32; o > 0; o >>= 1) s += __shfl_down(s, o);
    s = __shfl(s, 0);
    float nrm = sqrtf(s);
    dst[r * 64 + t] = v / fmaxf(nrm, 1e-12f);
}

// ---------------- sim[m][n] = d[m] . s[n]; rowmax over n ----------------
__global__ __launch_bounds__(256) void sim_kernel(const float* dn, const float* sn,
                                                  float* sim, float* rmax) {
    __shared__ __align__(16) float dv[64];
    __shared__ float red[256];
    int m = blockIdx.x, t = threadIdx.x;
    if (t < 64) dv[t] = dn[m * 64 + t];
    __syncthreads();
    float acc = 0.f;
    const float4* sp = (const float4*)(sn + t * 64);
    const float4* dp = (const float4*)dv;
    for (int i = 0; i < 16; i++) {
        float4 s4 = sp[i], d4 = dp[i];
        acc += s4.x * d4.x + s4.y * d4.y + s4.z * d4.z + s4.w * d4.w;
    }
    sim[m * 256 + t] = acc;
    red[t] = acc; __syncthreads();
    for (int s = 128; s > 0; s >>= 1) {
        if (t < s) red[t] = fmaxf(red[t], red[t + s]);
        __syncthreads();
    }
    if (t == 0) rmax[m] = red[0];
}

// ---------------- colmax over m per n ----------------
__global__ __launch_bounds__(256) void colmax_kernel(const float* sim, float* cmax) {
    __shared__ float red[256];
    int n = blockIdx.x, t = threadIdx.x;
    float mx = -INFINITY;
    for (int m = t; m < 1024; m += 256) mx = fmaxf(mx, sim[m * 256 + n]);
    red[t] = mx; __syncthreads();
    for (int s = 128; s > 0; s >>= 1) {
        if (t < s) red[t] = fmaxf(red[t], red[t + s]);
        __syncthreads();
    }
    if (t == 0) cmax[n] = red[0];
}

// ---------------- 16-NN per point ----------------
__global__ __launch_bounds__(256) void knn_kernel(float* ws) {
    const float* xyz = ws + WS_XYZ;
    int* knn = (int*)(ws + WS_KNN);
    __shared__ float px[256], py[256], pz[256], d2[256];
    __shared__ float rv[256];
    __shared__ int   ri[256];
    int n = blockIdx.x, t = threadIdx.x;
    px[t] = xyz[t * 3 + 0]; py[t] = xyz[t * 3 + 1]; pz[t] = xyz[t * 3 + 2];
    __syncthreads();
    float dx = px[t] - px[n], dy = py[t] - py[n], dz = pz[t] - pz[n];
    d2[t] = dx * dx + dy * dy + dz * dz;
    __syncthreads();
    for (int k = 0; k < 16; k++) {
        rv[t] = d2[t]; ri[t] = t;
        __syncthreads();
        for (int s = 128; s > 0; s >>= 1) {
            if (t < s) {
                float v2 = rv[t + s]; int i2 = ri[t + s];
                if (v2 < rv[t] || (v2 == rv[t] && i2 < ri[t])) { rv[t] = v2; ri[t] = i2; }
            }
            __syncthreads();
        }
        if (t == 0) { knn[n * 16 + k] = ri[0]; d2[ri[0]] = INFINITY; }
        __syncthreads();
    }
}

// ---------------- point branch: MLP2 over 16 neighbors -> pc_feats ----------------
__global__ __launch_bounds__(256) void mlp2_kernel(float* ws, const float* wpts,
        const float* w0, const float* b0, const float* w1, const float* b1,
        const float* w2, const float* b2) {
    __shared__ float wA[68 * 64], wB[64 * 64], wC[64 * 64];
    __shared__ float bA[64], bB[64], bC[64];
    __shared__ float x[16 * 68], hA[16 * 68], hB[16 * 68];
    __shared__ int   kn[16];
    __shared__ float wv[16], wts[16];
    int n = blockIdx.x, t = threadIdx.x;
    const float* xyz = ws + WS_XYZ;
    const int* knn = (const int*)(ws + WS_KNN);
    for (int i = t; i < 68 * 64; i += 256) wA[i] = w0[i];
    for (int i = t; i < 64 * 64; i += 256) { wB[i] = w1[i]; wC[i] = w2[i]; }
    if (t < 64) { bA[t] = b0[t]; bB[t] = b1[t]; bC[t] = b2[t]; }
    if (t < 16) kn[t] = knn[n * 16 + t];
    __syncthreads();
    for (int i = t; i < 1024; i += 256) {
        int k = i >> 6, c = i & 63;
        x[k * 68 + c] = wpts[kn[k] * 64 + c];
    }
    if (t < 16) {
        int i = kn[t];
        float dx = xyz[i * 3 + 0] - xyz[n * 3 + 0];
        float dy = xyz[i * 3 + 1] - xyz[n * 3 + 1];
        float dz = xyz[i * 3 + 2] - xyz[n * 3 + 2];
        x[t * 68 + 64] = dx; x[t * 68 + 65] = dy; x[t * 68 + 66] = dz;
        x[t * 68 + 67] = sqrtf(dx * dx + dy * dy + dz * dz);
    }
    __syncthreads();
    for (int o = t; o < 1024; o += 256) {
        int k = o >> 6, j = o & 63; float acc = bA[j];
        for (int i = 0; i < 68; i++) acc += x[k * 68 + i] * wA[i * 64 + j];
        hA[k * 68 + j] = fmaxf(acc, 0.f);
    }
    __syncthreads();
    for (int o = t; o < 1024; o += 256) {
        int k = o >> 6, j = o & 63; float acc = bB[j];
        for (int i = 0; i < 64; i++) acc += hA[k * 68 + i] * wB[i * 64 + j];
        hB[k * 68 + j] = fmaxf(acc, 0.f);
    }
    __syncthreads();
    for (int o = t; o < 1024; o += 256) {
        int k = o >> 6, j = o & 63; float acc = bC[j];
        for (int i = 0; i < 64; i++) acc += hB[k * 68 + i] * wC[i * 64 + j];
        hA[k * 68 + j] = fmaxf(acc, 0.f);   // h3 overwrites h1 buffer
    }
    __syncthreads();
    if (t < 16) {
        float mx = -INFINITY;
        for (int j = 0; j < 64; j++) mx = fmaxf(mx, hA[t * 68 + j]);
        wv[t] = mx;
    }
    __syncthreads();
    if (t < 16) {
        float mx = -INFINITY;
        for (int k = 0; k < 16; k++) mx = fmaxf(mx, wv[k]);
        float sum = 0.f;
        for (int k = 0; k < 16; k++) sum += expf(wv[k] - mx);
        wts[t] = expf(wv[t] - mx) / sum;
    }
    __syncthreads();
    if (t < 64) {
        float acc = 0.f;
        for (int k = 0; k < 16; k++) acc += wts[k] * x[k * 68 + t];
        ws[WS_PCF + n * 64 + t] = acc;
    }
}

// ---------------- image branch: MLP3 over 3x3 window -> img_feats ----------------
__global__ __launch_bounds__(256) void mlp3_kernel(float* ws,
        const float* w0, const float* b0, const float* w1, const float* b1,
        const float* w2, const float* b2) {
    __shared__ float wA[67 * 64], wB[64 * 64], wC[64 * 64];
    __shared__ float bA[64], bB[64], bC[64];
    __shared__ float x[9 * 68], hA[9 * 68], hB[9 * 68];
    __shared__ float wv[9], iw[9];
    int m = blockIdx.x, t = threadIdx.x;
    int y = m >> 5, xx = m & 31;
    const float* rf = ws + WS_RF;
    const float* rfi = ws + WS_RFI;
    for (int i = t; i < 67 * 64; i += 256) wA[i] = w0[i];
    for (int i = t; i < 64 * 64; i += 256) { wB[i] = w1[i]; wC[i] = w2[i]; }
    if (t < 64) { bA[t] = b0[t]; bB[t] = b1[t]; bC[t] = b2[t]; }
    if (t < 27) {
        int kk = t / 3, c = t - kk * 3;
        int dy = kk / 3 - 1, dxo = kk % 3 - 1;
        int ny = y + dy, nx = xx + dxo;
        bool val = (ny >= 0 && ny < 32 && nx >= 0 && nx < 32);
        int m2 = ny * 32 + nx;
        x[kk * 68 + c] = val ? rfi[m2 * 3 + c] : 0.f;
    }
    __syncthreads();
    for (int i = t; i < 576; i += 256) {
        int kk = i >> 6, c = i & 63;
        int dy = kk / 3 - 1, dxo = kk % 3 - 1;
        int ny = y + dy, nx = xx + dxo;
        bool val = (ny >= 0 && ny < 32 && nx >= 0 && nx < 32);
        int m2 = ny * 32 + nx;
        x[kk * 68 + 3 + c] = val ? rf[m2 * 64 + c] : 0.f;
    }
    __syncthreads();
    for (int o = t; o < 576; o += 256) {
        int k = o >> 6, j = o & 63; float acc = bA[j];
        for (int i = 0; i < 67; i++) acc += x[k * 68 + i] * wA[i * 64 + j];
        hA[k * 68 + j] = fmaxf(acc, 0.f);
    }
    __syncthreads();
    for (int o = t; o < 576; o += 256) {
        int k = o >> 6, j = o & 63; float acc = bB[j];
        for (int i = 0; i < 64; i++) acc += hA[k * 68 + i] * wB[i * 64 + j];
        hB[k * 68 + j] = fmaxf(acc, 0.f);
    }
    __syncthreads();
    for (int o = t; o < 576; o += 256) {
        int k = o >> 6, j = o & 63; float acc = bC[j];
        for (int i = 0; i < 64; i++) acc += hB[k * 68 + i] * wC[i * 64 + j];
        hA[k * 68 + j] = fmaxf(acc, 0.f);
    }
    __syncthreads();
    if (t < 9) {
        float mx = -INFINITY;
        for (int j = 0; j < 64; j++) mx = fmaxf(mx, hA[t * 68 + j]);
        wv[t] = mx;
    }
    __syncthreads();
    if (t < 9) {
        float mx = -INFINITY;
        for (int k = 0; k < 9; k++) mx = fmaxf(mx, wv[k]);
        float sum = 0.f;
        for (int k = 0; k < 9; k++) sum += expf(wv[k] - mx);
        iw[t] = expf(wv[t] - mx) / sum;
    }
    __syncthreads();
    if (t < 64) {
        float acc = 0.f;
        for (int k = 0; k < 9; k++) acc += iw[k] * x[k * 68 + 3 + t];
        ws[WS_IMGF + m * 64 + t] = acc;
    }
}

// ---------------- MLP1 layer-1 decomposition ----------------
__global__ __launch_bounds__(128) void base1_kernel(float* ws, const float* wpts,
                                                    const float* w10, const float* b10) {
    int n = blockIdx.x, j = threadIdx.x;
    float acc = b10[j];
    for (int i = 0; i < 3; i++)  acc += ws[WS_XYZ + n * 3 + i] * w10[i * 128 + j];
    for (int c = 0; c < 64; c++) acc += wpts[n * 64 + c] * w10[(6 + c) * 128 + j];
    ws[WS_B1 + n * 128 + j] = acc;
}
__global__ __launch_bounds__(128) void base2_kernel(float* ws, const float* w10) {
    int m = blockIdx.x, j = threadIdx.x;
    float acc = 0.f;
    for (int i = 0; i < 3; i++)  acc += ws[WS_RFI + m * 3 + i] * w10[(3 + i) * 128 + j];
    for (int c = 0; c < 64; c++) acc += ws[WS_RF + m * 64 + c] * w10[(70 + c) * 128 + j];
    ws[WS_B2 + m * 128 + j] = acc;
}

// ---------------- main fused MLP1 + partial online softmax ----------------
// grid (4, 256): blockIdx.x = m-segment (256 m each), blockIdx.y = n.
// Writes per-(n,seg) partials: M, S, unnormalized att (64) and uv (3).
__global__ __launch_bounds__(256) void mlp1_kernel(float* ws, const float* w10,
        const float* w11, const float* b11, const float* w12, const float* b12) {
    __shared__ __align__(16) float H1t[128 * 35];   // [k][row], pad stride 35 (bank spread)
    __shared__ __align__(16) float H2t[64 * 35];
    __shared__ __align__(16) float H3[32 * 68];     // [row][col]
    __shared__ float base1n[128];
    __shared__ float simw[4 * 128];                 // w1_0 rows 134..137
    __shared__ float simf[32 * 4];
    __shared__ float rfi3[32 * 3];
    __shared__ float rm[32], ew[32];
    int n = blockIdx.y, seg = blockIdx.x, t = threadIdx.x;
    const float* sim1 = ws + WS_SIM1;  const float* rm1g = ws + WS_RM1;
    const float* sim2 = ws + WS_SIM2;  const float* rm2g = ws + WS_RM2;
    const float* base2 = ws + WS_B2;   const float* rfig = ws + WS_RFI;
    float cm1 = ws[WS_CM1 + n], cm2 = ws[WS_CM2 + n];
    if (t < 128) base1n[t] = ws[WS_B1 + n * 128 + t];
    for (int i = t; i < 512; i += 256) simw[i] = w10[134 * 128 + i];
    int rg = t >> 4, cg = t & 15;
    float4 bias2 = *(const float4*)&b11[cg * 4];
    float4 bias3 = *(const float4*)&b12[cg * 4];
    float attAcc = 0.f, uvAcc = 0.f;
    float Mv = -INFINITY, Sv = 0.f;
    __syncthreads();
    int mBeg = seg * 256, mEnd = mBeg + 256;
    for (int m0 = mBeg; m0 < mEnd; m0 += 32) {
        if (t < 32) {
            int m = m0 + t;
            float s1 = sim1[m * 256 + n], r1 = rm1g[m];
            float s2 = sim2[m * 256 + n], r2 = rm2g[m];
            simf[t * 4 + 0] = s1 / (cm1 + 1e-6f);
            simf[t * 4 + 1] = s1 / (r1 + 1e-10f);
            simf[t * 4 + 2] = s2 / (cm2 + 1e-6f);
            simf[t * 4 + 3] = s2 / (r2 + 1e-10f);
        } else if (t >= 64 && t < 160) {
            int i = t - 64; int row = i / 3, c = i - row * 3;
            rfi3[i] = rfig[(m0 + row) * 3 + c];
        }
        __syncthreads();
        // layer 1 combine: H1t[k][row]
        for (int idx = t; idx < 4096; idx += 256) {
            int k = idx & 127, row = idx >> 7;
            int m = m0 + row;
            float v = base1n[k] + base2[m * 128 + k]
                    + simf[row * 4 + 0] * simw[0 * 128 + k]
                    + simf[row * 4 + 1] * simw[1 * 128 + k]
                    + simf[row * 4 + 2] * simw[2 * 128 + k]
                    + simf[row * 4 + 3] * simw[3 * 128 + k];
            H1t[k * 35 + row] = fmaxf(v, 0.f);
        }
        __syncthreads();
        // layer 2: 32 rows x 64 cols, thread tile 2x4
        {
            float a00 = bias2.x, a01 = bias2.y, a02 = bias2.z, a03 = bias2.w;
            float a10 = bias2.x, a11 = bias2.y, a12 = bias2.z, a13 = bias2.w;
            for (int k = 0; k < 128; k++) {
                float2 av = *(const float2*)&H1t[k * 35 + rg * 2];
                float4 bv = *(const float4*)&w11[k * 64 + cg * 4];
                a00 += av.x * bv.x; a01 += av.x * bv.y; a02 += av.x * bv.z; a03 += av.x * bv.w;
                a10 += av.y * bv.x; a11 += av.y * bv.y; a12 += av.y * bv.z; a13 += av.y * bv.w;
            }
            *(float2*)&H2t[(cg * 4 + 0) * 35 + rg * 2] = make_float2(fmaxf(a00, 0.f), fmaxf(a10, 0.f));
            *(float2*)&H2t[(cg * 4 + 1) * 35 + rg * 2] = make_float2(fmaxf(a01, 0.f), fmaxf(a11, 0.f));
            *(float2*)&H2t[(cg * 4 + 2) * 35 + rg * 2] = make_float2(fmaxf(a02, 0.f), fmaxf(a12, 0.f));
            *(float2*)&H2t[(cg * 4 + 3) * 35 + rg * 2] = make_float2(fmaxf(a03, 0.f), fmaxf(a13, 0.f));
        }
        __syncthreads();
        // layer 3
        {
            float c00 = bias3.x, c01 = bias3.y, c02 = bias3.z, c03 = bias3.w;
            float c10 = bias3.x, c11 = bias3.y, c12 = bias3.z, c13 = bias3.w;
            for (int k = 0; k < 64; k++) {
                float2 av = *(const float2*)&H2t[k * 35 + rg * 2];
                float4 bv = *(const float4*)&w12[k * 64 + cg * 4];
                c00 += av.x * bv.x; c01 += av.x * bv.y; c02 += av.x * bv.z; c03 += av.x * bv.w;
                c10 += av.y * bv.x; c11 += av.y * bv.y; c12 += av.y * bv.z; c13 += av.y * bv.w;
            }
            *(float4*)&H3[(rg * 2 + 0) * 68 + cg * 4] =
                make_float4(fmaxf(c00, 0.f), fmaxf(c01, 0.f), fmaxf(c02, 0.f), fmaxf(c03, 0.f));
            *(float4*)&H3[(rg * 2 + 1) * 68 + cg * 4] =
                make_float4(fmaxf(c10, 0.f), fmaxf(c11, 0.f), fmaxf(c12, 0.f), fmaxf(c13, 0.f));
        }
        __syncthreads();
        if (t < 32) {
            float mx = -INFINITY;
            for (int c = 0; c < 64; c++) mx = fmaxf(mx, H3[t * 68 + c]);
            rm[t] = mx;
        }
        __syncthreads();
        float tmax = -INFINITY;
        for (int r = 0; r < 32; r++) tmax = fmaxf(tmax, rm[r]);
        float newM = fmaxf(Mv, tmax);
        float rescale = expf(Mv - newM);
        if (t < 32) ew[t] = expf(rm[t] - newM);
        Mv = newM;
        __syncthreads();
        float sumew = 0.f;
        for (int r = 0; r < 32; r++) sumew += ew[r];
        Sv = Sv * rescale + sumew;
        if (t < 64) {
            float acc = 0.f;
            for (int r = 0; r < 32; r++) acc += ew[r] * H3[r * 68 + t];
            attAcc = attAcc * rescale + acc;
        } else if (t < 67) {
            int c = t - 64; float acc = 0.f;
            for (int r = 0; r < 32; r++) acc += ew[r] * rfi3[r * 3 + c];
            uvAcc = uvAcc * rescale + acc;
        }
        __syncthreads();
    }
    int p = n * 4 + seg;
    if (t == 0) { ws[WS_PM + p] = Mv; ws[WS_PS + p] = Sv; }
    if (t < 64) ws[WS_PATT + p * 64 + t] = attAcc;
    else if (t < 67) ws[WS_PUV + p * 3 + (t - 64)] = uvAcc;
}

// ---------------- merge the 4 m-segments (exact flash-style combine) ----------------
__global__ __launch_bounds__(128) void combine_kernel(float* ws) {
    int n = blockIdx.x, t = threadIdx.x;
    float pm[4], e[4];
    float M = -INFINITY;
    for (int s = 0; s < 4; s++) { pm[s] = ws[WS_PM + n * 4 + s]; M = fmaxf(M, pm[s]); }
    float S = 0.f;
    for (int s = 0; s < 4; s++) { e[s] = expf(pm[s] - M); S += ws[WS_PS + n * 4 + s] * e[s]; }
    if (t < 64) {
        float acc = 0.f;
        for (int s = 0; s < 4; s++) acc += ws[WS_PATT + (n * 4 + s) * 64 + t] * e[s];
        ws[WS_ATT + n * 64 + t] = acc / S;
    } else if (t < 67) {
        int c = t - 64; float acc = 0.f;
        for (int s = 0; s < 4; s++) acc += ws[WS_PUV + (n * 4 + s) * 3 + c] * e[s];
        ws[WS_UV + n * 3 + c] = acc / S;
    }
}

// ---------------- head MLP -> weights (d_out), w_in ----------------
__global__ __launch_bounds__(128) void head_kernel(float* ws,
        const float* wm0, const float* bm0, const float* wm1, const float* bm1,
        const float* wm2, const float* bm2, float* out) {
    __shared__ float av[64], ha[64], hb[128], lg[2];
    int n = blockIdx.x, t = threadIdx.x;
    if (t < 64) av[t] = ws[WS_ATT + n * 64 + t];
    __syncthreads();
    if (t < 64) {
        float acc = bm0[t];
        for (int i = 0; i < 64; i++) acc += av[i] * wm0[i * 64 + t];
        ha[t] = fmaxf(acc, 0.f);
    }
    __syncthreads();
    {
        float acc = bm1[t];
        for (int i = 0; i < 64; i++) acc += ha[i] * wm1[i * 128 + t];
        hb[t] = fmaxf(acc, 0.f);
    }
    __syncthreads();
    if (t < 2) {
        float acc = bm2[t];
        for (int i = 0; i < 128; i++) acc += hb[i] * wm2[i * 2 + t];
        lg[t] = acc;
    }
    __syncthreads();
    if (t == 0) {
        float l0 = lg[0], l1 = lg[1];
        float mx = fmaxf(l0, l1);
        float e0 = expf(l0 - mx), e1 = expf(l1 - mx);
        float s = e0 + e1;
        out[12 + n * 2 + 0] = e0 / s;
        out[12 + n * 2 + 1] = e1 / s;
        ws[WS_WIN + n] = (e1 > e0) ? 1.f : 0.f;
    }
}

// ---------------- weighted PnP (Kabsch with 3x3 SVD, double) ----------------
__device__ void compute_rt(const double Hm[9], const double sc[3], const double dc[3],
                           float* out) {
    double Hd[3][3] = {{Hm[0], Hm[1], Hm[2]}, {Hm[3], Hm[4], Hm[5]}, {Hm[6], Hm[7], Hm[8]}};
    double A[3][3], V[3][3] = {{1, 0, 0}, {0, 1, 0}, {0, 0, 1}};
    for (int i = 0; i < 3; i++)
        for (int j = 0; j < 3; j++) {
            double s = 0;
            for (int k = 0; k < 3; k++) s += Hd[k][i] * Hd[k][j];
            A[i][j] = s;
        }
    for (int sweep = 0; sweep < 50; sweep++) {
        double off = fabs(A[0][1]) + fabs(A[0][2]) + fabs(A[1][2]);
        if (off < 1e-28) break;
        const int PQ[3][2] = {{0, 1}, {0, 2}, {1, 2}};
        for (int pp = 0; pp < 3; pp++) {
            int p = PQ[pp][0], q = PQ[pp][1];
            double apq = A[p][q];
            if (fabs(apq) < 1e-300) continue;
            double tau = (A[q][q] - A[p][p]) / (2.0 * apq);
            double tt = (tau >= 0.0 ? 1.0 : -1.0) / (fabs(tau) + sqrt(1.0 + tau * tau));
            double c = 1.0 / sqrt(1.0 + tt * tt), s = tt * c;
            for (int k = 0; k < 3; k++) {
                double akp = A[k][p], akq = A[k][q];
                A[k][p] = c * akp - s * akq; A[k][q] = s * akp + c * akq;
            }
            for (int k = 0; k < 3; k++) {
                double apk = A[p][k], aqk = A[q][k];
                A[p][k] = c * apk - s * aqk; A[q][k] = s * apk + c * aqk;
            }
            for (int k = 0; k < 3; k++) {
                double vkp = V[k][p], vkq = V[k][q];
                V[k][p] = c * vkp - s * vkq; V[k][q] = s * vkp + c * vkq;
            }
        }
    }
    double lam[3] = {A[0][0], A[1][1], A[2][2]};
    int o0 = 0, o1 = 1, o2 = 2;
    if (lam[o0] < lam[o1]) { int tp = o0; o0 = o1; o1 = tp; }
    if (lam[o0] < lam[o2]) { int tp = o0; o0 = o2; o2 = tp; }
    if (lam[o1] < lam[o2]) { int tp = o1; o1 = o2; o2 = tp; }
    int ord[3] = {o0, o1, o2};
    double v[3][3], u[3][3], R[3][3];
    for (int k = 0; k < 3; k++)
        for (int i = 0; i < 3; i++) v[k][i] = V[i][ord[k]];
    double sv0 = sqrt(fmax(lam[o0], 0.0));
    if (!(sv0 > 1e-150)) {
        for (int i = 0; i < 3; i++)
            for (int j = 0; j < 3; j++) R[i][j] = (i == j) ? 1.0 : 0.0;
    } else {
        double nn[3];
        for (int k = 0; k < 3; k++) {
            for (int i = 0; i < 3; i++)
                u[k][i] = Hd[i][0] * v[k][0] + Hd[i][1] * v[k][1] + Hd[i][2] * v[k][2];
            nn[k] = sqrt(u[k][0] * u[k][0] + u[k][1] * u[k][1] + u[k][2] * u[k][2]);
        }
        for (int i = 0; i < 3; i++) u[0][i] /= nn[0];
        if (nn[1] > 1e-12 * nn[0]) {
            for (int i = 0; i < 3; i++) u[1][i] /= nn[1];
        } else {
            int e = (fabs(u[0][0]) <= fabs(u[0][1]) && fabs(u[0][0]) <= fabs(u[0][2])) ? 0
                    : ((fabs(u[0][1]) <= fabs(u[0][2])) ? 1 : 2);
            double ev[3] = {0, 0, 0}; ev[e] = 1.0;
            double d0 = ev[0] * u[0][0] + ev[1] * u[0][1] + ev[2] * u[0][2];
            double w1v[3], wn2 = 0;
            for (int i = 0; i < 3; i++) { w1v[i] = ev[i] - d0 * u[0][i]; wn2 += w1v[i] * w1v[i]; }
            wn2 = sqrt(wn2);
            for (int i = 0; i < 3; i++) u[1][i] = w1v[i] / wn2;
        }
        if (nn[2] > 1e-10 * nn[0]) {
            for (int i = 0; i < 3; i++) u[2][i] /= nn[2];
        } else {
            u[2][0] = u[0][1] * u[1][2] - u[0][2] * u[1][1];
            u[2][1] = u[0][2] * u[1][0] - u[0][0] * u[1][2];
            u[2][2] = u[0][0] * u[1][1] - u[0][1] * u[1][0];
        }
        double cr[3] = {u[1][1] * u[2][2] - u[1][2] * u[2][1],
                        u[1][2] * u[2][0] - u[1][0] * u[2][2],
                        u[1][0] * u[2][1] - u[1][1] * u[2][0]};
        double detU = u[0][0] * cr[0] + u[0][1] * cr[1] + u[0][2] * cr[2];
        double cv[3] = {v[1][1] * v[2][2] - v[1][2] * v[2][1],
                        v[1][2] * v[2][0] - v[1][0] * v[2][2],
                        v[1][0] * v[2][1] - v[1][1] * v[2][0]};
        double detV = v[0][0] * cv[0] + v[0][1] * cv[1] + v[0][2] * cv[2];
        double dsign = detU * detV;
        for (int i = 0; i < 3; i++)
            for (int j = 0; j < 3; j++)
                R[i][j] = v[0][i] * u[0][j] + v[1][i] * u[1][j] + dsign * v[2][i] * u[2][j];
    }
    for (int i = 0; i < 3; i++) {
        double ti = dc[i] - (R[i][0] * sc[0] + R[i][1] * sc[1] + R[i][2] * sc[2]);
        out[9 + i] = (float)ti;
        for (int j = 0; j < 3; j++) out[i * 3 + j] = (float)R[i][j];
    }
}

__global__ __launch_bounds__(256) void pnp_kernel(float* ws, float* out) {
    __shared__ double red[256];
    int t = threadIdx.x;
    double w = (double)ws[WS_WIN + t];
    double x0 = ws[WS_XYZ + t * 3 + 0];
    double x1 = ws[WS_XYZ + t * 3 + 1];
    double x2 = ws[WS_XYZ + t * 3 + 2];
    double z = x2;
    double dd0 = (double)ws[WS_UV + t * 3 + 0] * z;
    double dd1 = (double)ws[WS_UV + t * 3 + 1] * z;
    double dd2 = z;
    auto reduce = [&](double v) -> double {
        red[t] = v; __syncthreads();
        for (int s = 128; s > 0; s >>= 1) {
            if (t < s) red[t] += red[t + s];
            __syncthreads();
        }
        double r = red[0]; __syncthreads();
        return r;
    };
    double wsum = reduce(w);
    double sx0 = reduce(w * x0), sx1 = reduce(w * x1), sx2 = reduce(w * x2);
    double sd0 = reduce(w * dd0), sd1 = reduce(w * dd1), sd2 = reduce(w * dd2);
    double inv = 1.0 / (wsum + 1e-8);
    double sc[3] = {sx0 * inv, sx1 * inv, sx2 * inv};
    double dc[3] = {sd0 * inv, sd1 * inv, sd2 * inv};
    double wn = w * inv;
    double a0 = x0 - sc[0], a1 = x1 - sc[1], a2 = x2 - sc[2];
    double b0 = dd0 - dc[0], b1 = dd1 - dc[1], b2 = dd2 - dc[2];
    double Hm[9];
    Hm[0] = reduce(wn * a0 * b0); Hm[1] = reduce(wn * a0 * b1); Hm[2] = reduce(wn * a0 * b2);
    Hm[3] = reduce(wn * a1 * b0); Hm[4] = reduce(wn * a1 * b1); Hm[5] = reduce(wn * a1 * b2);
    Hm[6] = reduce(wn * a2 * b0); Hm[7] = reduce(wn * a2 * b1); Hm[8] = reduce(wn * a2 * b2);
    if (t == 0) compute_rt(Hm, sc, dc, out);
}

// ---------------- launch ----------------
extern "C" void kernel_launch(void* const* d_in, const int* in_sizes, int n_in,
                              void* d_out, int out_size, void* d_ws, size_t ws_size,
                              hipStream_t stream) {
    float* ws = (float*)d_ws;
    const float* wxyz = (const float*)d_in[0];
    const float* wpts = (const float*)d_in[1];
    const float* RF3  = (const float*)d_in[2];
    const float* RFI  = (const float*)d_in[3];
    const float* lz   = (const float*)d_in[4];
    const float* w2_0 = (const float*)d_in[5];  const float* b2_0 = (const float*)d_in[6];
    const float* w2_1 = (const float*)d_in[7];  const float* b2_1 = (const float*)d_in[8];
    const float* w2_2 = (const float*)d_in[9];  const float* b2_2 = (const float*)d_in[10];
    const float* w3_0 = (const float*)d_in[11]; const float* b3_0 = (const float*)d_in[12];
    const float* w3_1 = (const float*)d_in[13]; const float* b3_1 = (const float*)d_in[14];
    const float* w3_2 = (const float*)d_in[15]; const float* b3_2 = (const float*)d_in[16];
    const float* w1_0 = (const float*)d_in[17]; const float* b1_0 = (const float*)d_in[18];
    const float* w1_1 = (const float*)d_in[19]; const float* b1_1 = (const float*)d_in[20];
    const float* w1_2 = (const float*)d_in[21]; const float* b1_2 = (const float*)d_in[22];
    const float* wm_0 = (const float*)d_in[23]; const float* bm_0 = (const float*)d_in[24];
    const float* wm_1 = (const float*)d_in[25]; const float* bm_1 = (const float*)d_in[26];
    const float* wm_2 = (const float*)d_in[27]; const float* bm_2 = (const float*)d_in[28];
    float* out = (float*)d_out;

    prep_kernel<<<272, 256, 0, stream>>>(ws, wxyz, lz, RF3, RFI);
    rownorm_kernel<<<256, 64, 0, stream>>>(wpts, ws + WS_SN);
    rownorm_kernel<<<1024, 64, 0, stream>>>(ws + WS_RF, ws + WS_DN);
    sim_kernel<<<1024, 256, 0, stream>>>(ws + WS_DN, ws + WS_SN, ws + WS_SIM1, ws + WS_RM1);
    colmax_kernel<<<256, 256, 0, stream>>>(ws + WS_SIM1, ws + WS_CM1);
    knn_kernel<<<256, 256, 0, stream>>>(ws);
    mlp2_kernel<<<256, 256, 0, stream>>>(ws, wpts, w2_0, b2_0, w2_1, b2_1, w2_2, b2_2);
    mlp3_kernel<<<1024, 256, 0, stream>>>(ws, w3_0, b3_0, w3_1, b3_1, w3_2, b3_2);
    rownorm_kernel<<<256, 64, 0, stream>>>(ws + WS_PCF, ws + WS_PCN);
    rownorm_kernel<<<1024, 64, 0, stream>>>(ws + WS_IMGF, ws + WS_IMGN);
    sim_kernel<<<1024, 256, 0, stream>>>(ws + WS_IMGN, ws + WS_PCN, ws + WS_SIM2, ws + WS_RM2);
    colmax_kernel<<<256, 256, 0, stream>>>(ws + WS_SIM2, ws + WS_CM2);
    base1_kernel<<<256, 128, 0, stream>>>(ws, wpts, w1_0, b1_0);
    base2_kernel<<<1024, 128, 0, stream>>>(ws, w1_0);
    mlp1_kernel<<<dim3(4, 256), 256, 0, stream>>>(ws, w1_0, w1_1, b1_1, w1_2, b1_2);
    combine_kernel<<<256, 128, 0, stream>>>(ws);
    head_kernel<<<256, 128, 0, stream>>>(ws, wm_0, bm_0, wm_1, bm_1, wm_2, bm_2, out);
    pnp_kernel<<<1, 256, 0, stream>>>(ws, out);
}

// Round 3
// 290.390 us; speedup vs baseline: 2.3655x; 2.1391x over previous
//
#include <hip/hip_runtime.h>
#include <math.h>

// Problem constants
// B=1, N=256, H=32, W=32, M=1024, C_LIDAR=C_RGB=64, K=16, S=3, MLP3=[128,64,64]

typedef _Float16 f16;
typedef __attribute__((ext_vector_type(8))) _Float16 f16x8;
typedef __attribute__((ext_vector_type(4))) float f32x4;

// ---------------- workspace layout (float offsets) ----------------
constexpr int WS_XYZ  = 0;                  // 256*3
constexpr int WS_RF   = 768;                // 1024*64
constexpr int WS_RFI  = WS_RF   + 65536;    // 1024*3
constexpr int WS_SN   = WS_RFI  + 3072;     // 256*64   l2norm(warped_points)
constexpr int WS_DN   = WS_SN   + 16384;    // 1024*64  l2norm(rf)
constexpr int WS_SIM1 = WS_DN   + 65536;    // 1024*256 sim[m][n]
constexpr int WS_RM1  = WS_SIM1 + 262144;   // 1024 max over n
constexpr int WS_CM1  = WS_RM1  + 1024;     // 256  max over m
constexpr int WS_PCF  = WS_CM1  + 256;      // 256*64
constexpr int WS_IMGF = WS_PCF  + 16384;    // 1024*64
constexpr int WS_PCN  = WS_IMGF + 65536;    // 256*64
constexpr int WS_IMGN = WS_PCN  + 16384;    // 1024*64
constexpr int WS_SIM2 = WS_IMGN + 65536;    // 1024*256
constexpr int WS_RM2  = WS_SIM2 + 262144;   // 1024
constexpr int WS_CM2  = WS_RM2  + 1024;     // 256
constexpr int WS_B1   = WS_CM2  + 256;      // 256*128  n-only part of MLP1 layer1 (incl bias)
constexpr int WS_B2   = WS_B1   + 32768;    // 1024*128 m-only part of MLP1 layer1
constexpr int WS_ATT  = WS_B2   + 131072;   // 256*64
constexpr int WS_UV   = WS_ATT  + 16384;    // 256*3
constexpr int WS_WIN  = WS_UV   + 768;      // 256
constexpr int WS_KNN  = WS_WIN  + 256;      // 256*16 ints
constexpr int WS_PM   = WS_KNN  + 4096;     // 256*4 partial max
constexpr int WS_PS   = WS_PM   + 1024;     // 256*4 partial sum
constexpr int WS_PATT = WS_PS   + 1024;     // 256*4*64 partial att
constexpr int WS_PUV  = WS_PATT + 65536;    // 256*4*3 partial uv
constexpr int WS_W11T = WS_PUV  + 3072;     // 4096 floats = 8192 f16 (w1_1^T [col][k])
constexpr int WS_W12T = WS_W11T + 4096;     // 2048 floats = 4096 f16 (w1_2^T [col][k])
constexpr int WS_G3   = WS_W12T + 2048;     // 1025*64 (MLP3 layer-1 per-pixel, row 1024 = relu(b))
// total ~= 4.7 MB

// ---------------- prep: xyz, rf, rfi transposes ----------------
__global__ __launch_bounds__(256) void prep_kernel(float* ws, const float* wxyz,
                                                   const float* lz, const float* RF3,
                                                   const float* RFI) {
    int i = blockIdx.x * 256 + threadIdx.x;
    if (i < 768) {
        int n = i / 3;
        ws[WS_XYZ + i] = wxyz[i] * lz[n];
    } else if (i < 768 + 65536) {
        int j = i - 768; int mm = j >> 6, c = j & 63;
        ws[WS_RF + j] = RF3[c * 1024 + mm];
    } else if (i < 768 + 65536 + 3072) {
        int j = i - (768 + 65536); int mm = j / 3, c = j - mm * 3;
        ws[WS_RFI + j] = RFI[c * 1024 + mm];
    }
}

// ---------------- f16 transposed weights for MFMA ----------------
__global__ __launch_bounds__(256) void prepw_kernel(float* ws, const float* w11,
                                                    const float* w12) {
    f16* w11t = (f16*)(ws + WS_W11T);
    f16* w12t = (f16*)(ws + WS_W12T);
    int i = blockIdx.x * 256 + threadIdx.x;
    if (i < 8192) {
        int col = i >> 7, k = i & 127;
        w11t[col * 128 + k] = (f16)w11[k * 64 + col];
    } else if (i < 12288) {
        int j = i - 8192; int col = j >> 6, k = j & 63;
        w12t[col * 64 + k] = (f16)w12[k * 64 + col];
    }
}

// ---------------- row L2-normalize (64 cols) ----------------
__global__ __launch_bounds__(64) void rownorm_kernel(const float* src, float* dst) {
    int r = blockIdx.x, t = threadIdx.x;
    float v = src[r * 64 + t];
    float s = v * v;
    for (int o = 32; o > 0; o >>= 1) s += __shfl_down(s, o);
    s = __shfl(s, 0);
    float nrm = sqrtf(s);
    dst[r * 64 + t] = v / fmaxf(nrm, 1e-12f);
}

// ---------------- sim[m][n] = d[m] . s[n]; rowmax over n ----------------
__global__ __launch_bounds__(256) void sim_kernel(const float* dn, const float* sn,
                                                  float* sim, float* rmax) {
    __shared__ __align__(16) float dv[64];
    __shared__ float red[256];
    int m = blockIdx.x, t = threadIdx.x;
    if (t < 64) dv[t] = dn[m * 64 + t];
    __syncthreads();
    float acc = 0.f;
    const float4* sp = (const float4*)(sn + t * 64);
    const float4* dp = (const float4*)dv;
    for (int i = 0; i < 16; i++) {
        float4 s4 = sp[i], d4 = dp[i];
        acc += s4.x * d4.x + s4.y * d4.y + s4.z * d4.z + s4.w * d4.w;
    }
    sim[m * 256 + t] = acc;
    red[t] = acc; __syncthreads();
    for (int s = 128; s > 0; s >>= 1) {
        if (t < s) red[t] = fmaxf(red[t], red[t + s]);
        __syncthreads();
    }
    if (t == 0) rmax[m] = red[0];
}

// ---------------- colmax over m per n ----------------
__global__ __launch_bounds__(256) void colmax_kernel(const float* sim, float* cmax) {
    __shared__ float red[256];
    int n = blockIdx.x, t = threadIdx.x;
    float mx = -INFINITY;
    for (int m = t; m < 1024; m += 256) mx = fmaxf(mx, sim[m * 256 + n]);
    red[t] = mx; __syncthreads();
    for (int s = 128; s > 0; s >>= 1) {
        if (t < s) red[t] = fmaxf(red[t], red[t + s]);
        __syncthreads();
    }
    if (t == 0) cmax[n] = red[0];
}

// ---------------- 16-NN per point ----------------
__global__ __launch_bounds__(256) void knn_kernel(float* ws) {
    const float* xyz = ws + WS_XYZ;
    int* knn = (int*)(ws + WS_KNN);
    __shared__ float px[256], py[256], pz[256], d2[256];
    __shared__ float rv[256];
    __shared__ int   ri[256];
    int n = blockIdx.x, t = threadIdx.x;
    px[t] = xyz[t * 3 + 0]; py[t] = xyz[t * 3 + 1]; pz[t] = xyz[t * 3 + 2];
    __syncthreads();
    float dx = px[t] - px[n], dy = py[t] - py[n], dz = pz[t] - pz[n];
    d2[t] = dx * dx + dy * dy + dz * dz;
    __syncthreads();
    for (int k = 0; k < 16; k++) {
        rv[t] = d2[t]; ri[t] = t;
        __syncthreads();
        for (int s = 128; s > 0; s >>= 1) {
            if (t < s) {
                float v2 = rv[t + s]; int i2 = ri[t + s];
                if (v2 < rv[t] || (v2 == rv[t] && i2 < ri[t])) { rv[t] = v2; ri[t] = i2; }
            }
            __syncthreads();
        }
        if (t == 0) { knn[n * 16 + k] = ri[0]; d2[ri[0]] = INFINITY; }
        __syncthreads();
    }
}

// ---------------- point branch: MLP2 over 16 neighbors -> pc_feats ----------------
__global__ __launch_bounds__(256) void mlp2_kernel(float* ws, const float* wpts,
        const float* w0, const float* b0, const float* w1, const float* b1,
        const float* w2, const float* b2) {
    __shared__ float wA[68 * 64], wB[64 * 64], wC[64 * 64];
    __shared__ float bA[64], bB[64], bC[64];
    __shared__ float x[16 * 68], hA[16 * 68], hB[16 * 68];
    __shared__ int   kn[16];
    __shared__ float wv[16], wts[16];
    int n = blockIdx.x, t = threadIdx.x;
    const float* xyz = ws + WS_XYZ;
    const int* knn = (const int*)(ws + WS_KNN);
    for (int i = t; i < 68 * 64; i += 256) wA[i] = w0[i];
    for (int i = t; i < 64 * 64; i += 256) { wB[i] = w1[i]; wC[i] = w2[i]; }
    if (t < 64) { bA[t] = b0[t]; bB[t] = b1[t]; bC[t] = b2[t]; }
    if (t < 16) kn[t] = knn[n * 16 + t];
    __syncthreads();
    for (int i = t; i < 1024; i += 256) {
        int k = i >> 6, c = i & 63;
        x[k * 68 + c] = wpts[kn[k] * 64 + c];
    }
    if (t < 16) {
        int i = kn[t];
        float dx = xyz[i * 3 + 0] - xyz[n * 3 + 0];
        float dy = xyz[i * 3 + 1] - xyz[n * 3 + 1];
        float dz = xyz[i * 3 + 2] - xyz[n * 3 + 2];
        x[t * 68 + 64] = dx; x[t * 68 + 65] = dy; x[t * 68 + 66] = dz;
        x[t * 68 + 67] = sqrtf(dx * dx + dy * dy + dz * dz);
    }
    __syncthreads();
    for (int o = t; o < 1024; o += 256) {
        int k = o >> 6, j = o & 63; float acc = bA[j];
        for (int i = 0; i < 68; i++) acc += x[k * 68 + i] * wA[i * 64 + j];
        hA[k * 68 + j] = fmaxf(acc, 0.f);
    }
    __syncthreads();
    for (int o = t; o < 1024; o += 256) {
        int k = o >> 6, j = o & 63; float acc = bB[j];
        for (int i = 0; i < 64; i++) acc += hA[k * 68 + i] * wB[i * 64 + j];
        hB[k * 68 + j] = fmaxf(acc, 0.f);
    }
    __syncthreads();
    for (int o = t; o < 1024; o += 256) {
        int k = o >> 6, j = o & 63; float acc = bC[j];
        for (int i = 0; i < 64; i++) acc += hB[k * 68 + i] * wC[i * 64 + j];
        hA[k * 68 + j] = fmaxf(acc, 0.f);   // h3 overwrites h1 buffer
    }
    __syncthreads();
    if (t < 16) {
        float mx = -INFINITY;
        for (int j = 0; j < 64; j++) mx = fmaxf(mx, hA[t * 68 + j]);
        wv[t] = mx;
    }
    __syncthreads();
    if (t < 16) {
        float mx = -INFINITY;
        for (int k = 0; k < 16; k++) mx = fmaxf(mx, wv[k]);
        float sum = 0.f;
        for (int k = 0; k < 16; k++) sum += expf(wv[k] - mx);
        wts[t] = expf(wv[t] - mx) / sum;
    }
    __syncthreads();
    if (t < 64) {
        float acc = 0.f;
        for (int k = 0; k < 16; k++) acc += wts[k] * x[k * 68 + t];
        ws[WS_PCF + n * 64 + t] = acc;
    }
}

// ---------------- MLP3 layer-1 per-pixel GEMV (unfold is just a gather of this) ----
// G[m] = relu(b0 + rfi[m].W[0:3] + rf[m].W[3:67]); row 1024 = relu(b0) (zero padding)
__global__ __launch_bounds__(64) void g3_kernel(float* ws, const float* w0, const float* b0) {
    int m = blockIdx.x, j = threadIdx.x;
    float acc = b0[j];
    if (m < 1024) {
        for (int i = 0; i < 3; i++)  acc += ws[WS_RFI + m * 3 + i] * w0[i * 64 + j];
        for (int c = 0; c < 64; c++) acc += ws[WS_RF + m * 64 + c] * w0[(3 + c) * 64 + j];
    }
    ws[WS_G3 + m * 64 + j] = fmaxf(acc, 0.f);
}

// ---------------- image branch: layers 2/3 over gathered G -> img_feats ----------
// grid 256, each block does 4 pixels (36 patch rows).
__global__ __launch_bounds__(256) void mlp3_kernel(float* ws,
        const float* w1, const float* b1, const float* w2, const float* b2) {
    __shared__ float wB[64 * 64], wC[64 * 64];
    __shared__ float bB[64], bC[64];
    __shared__ float x1[36 * 68], h2[36 * 68];
    __shared__ float h3v[36], iw9[36];
    int m0 = blockIdx.x * 4, t = threadIdx.x;
    const float* G = ws + WS_G3;
    const float* rf = ws + WS_RF;
    for (int i = t; i < 4096; i += 256) { wB[i] = w1[i]; wC[i] = w2[i]; }
    if (t < 64) { bB[t] = b1[t]; bC[t] = b2[t]; }
    // gather layer-1 activations
    for (int i = t; i < 36 * 64; i += 256) {
        int row = i >> 6, c = i & 63;
        int mi = row / 9, kk = row - mi * 9;
        int m = m0 + mi; int y = m >> 5, x = m & 31;
        int dy = kk / 3 - 1, dx = kk % 3 - 1;
        int ny = y + dy, nx = x + dx;
        bool val = (ny >= 0 && ny < 32 && nx >= 0 && nx < 32);
        int idx = val ? (ny * 32 + nx) : 1024;
        x1[row * 68 + c] = G[idx * 64 + c];
    }
    __syncthreads();
    for (int o = t; o < 36 * 64; o += 256) {
        int row = o >> 6, c = o & 63; float acc = bB[c];
        for (int i = 0; i < 64; i++) acc += x1[row * 68 + i] * wB[i * 64 + c];
        h2[row * 68 + c] = fmaxf(acc, 0.f);
    }
    __syncthreads();
    for (int o = t; o < 36 * 64; o += 256) {
        int row = o >> 6, c = o & 63; float acc = bC[c];
        for (int i = 0; i < 64; i++) acc += h2[row * 68 + i] * wC[i * 64 + c];
        x1[row * 68 + c] = fmaxf(acc, 0.f);    // h3 overwrites x1
    }
    __syncthreads();
    if (t < 36) {
        float mx = -INFINITY;
        for (int c = 0; c < 64; c++) mx = fmaxf(mx, x1[t * 68 + c]);
        h3v[t] = mx;
    }
    __syncthreads();
    if (t < 36) {
        int mi = t / 9;
        float mx = -INFINITY;
        for (int k = 0; k < 9; k++) mx = fmaxf(mx, h3v[mi * 9 + k]);
        float sum = 0.f;
        for (int k = 0; k < 9; k++) sum += expf(h3v[mi * 9 + k] - mx);
        iw9[t] = expf(h3v[t] - mx) / sum;
    }
    __syncthreads();
    {
        int mi = t >> 6, c = t & 63;
        int m = m0 + mi; int y = m >> 5, x = m & 31;
        float acc = 0.f;
        for (int kk = 0; kk < 9; kk++) {
            int dy = kk / 3 - 1, dx = kk % 3 - 1;
            int ny = y + dy, nx = x + dx;
            bool val = (ny >= 0 && ny < 32 && nx >= 0 && nx < 32);
            if (val) acc += iw9[mi * 9 + kk] * rf[(ny * 32 + nx) * 64 + c];
        }
        ws[WS_IMGF + m * 64 + c] = acc;
    }
}

// ---------------- MLP1 layer-1 decomposition ----------------
__global__ __launch_bounds__(128) void base1_kernel(float* ws, const float* wpts,
                                                    const float* w10, const float* b10) {
    int n = blockIdx.x, j = threadIdx.x;
    float acc = b10[j];
    for (int i = 0; i < 3; i++)  acc += ws[WS_XYZ + n * 3 + i] * w10[i * 128 + j];
    for (int c = 0; c < 64; c++) acc += wpts[n * 64 + c] * w10[(6 + c) * 128 + j];
    ws[WS_B1 + n * 128 + j] = acc;
}
__global__ __launch_bounds__(128) void base2_kernel(float* ws, const float* w10) {
    int m = blockIdx.x, j = threadIdx.x;
    float acc = 0.f;
    for (int i = 0; i < 3; i++)  acc += ws[WS_RFI + m * 3 + i] * w10[(3 + i) * 128 + j];
    for (int c = 0; c < 64; c++) acc += ws[WS_RF + m * 64 + c] * w10[(70 + c) * 128 + j];
    ws[WS_B2 + m * 128 + j] = acc;
}

// ---------------- main fused MLP1 (MFMA f16 layers 2/3) + partial softmax -------
// grid (4, 256): blockIdx.x = m-segment (256 m), blockIdx.y = n. 4 waves/block:
// wave w owns output cols [w*16, w*16+16); weight B-fragments live in registers.
__global__ __launch_bounds__(256) void mlp1_kernel(float* ws, const float* w10,
        const float* b11, const float* b12) {
    __shared__ __align__(16) f16 H1h[32 * 136];   // [row][k], stride 136 halves
    __shared__ __align__(16) f16 H2h[32 * 72];    // [row][k], stride 72 halves
    __shared__ __align__(16) float H3[32 * 68];   // [row][col]
    __shared__ float base1n[128];
    __shared__ float simw[4 * 128];
    __shared__ float simf[32 * 4];
    __shared__ float rfi3[32 * 3];
    __shared__ float rm[32], ew[32];
    int n = blockIdx.y, seg = blockIdx.x, t = threadIdx.x;
    int wave = t >> 6, lane = t & 63, q = lane >> 4, l16 = lane & 15;
    int col = wave * 16 + l16;
    const float* sim1 = ws + WS_SIM1;  const float* rm1g = ws + WS_RM1;
    const float* sim2 = ws + WS_SIM2;  const float* rm2g = ws + WS_RM2;
    const float* base2 = ws + WS_B2;   const float* rfig = ws + WS_RFI;
    const f16* w11t = (const f16*)(ws + WS_W11T);
    const f16* w12t = (const f16*)(ws + WS_W12T);
    float cm1 = ws[WS_CM1 + n], cm2 = ws[WS_CM2 + n];
    if (t < 128) base1n[t] = ws[WS_B1 + n * 128 + t];
    for (int i = t; i < 512; i += 256) simw[i] = w10[134 * 128 + i];
    // per-block register-resident weight fragments (loop-invariant)
    f16x8 B2f[4], B3f[2];
    for (int s = 0; s < 4; s++) B2f[s] = *(const f16x8*)&w11t[col * 128 + s * 32 + q * 8];
    for (int s = 0; s < 2; s++) B3f[s] = *(const f16x8*)&w12t[col * 64 + s * 32 + q * 8];
    float bias2 = b11[col], bias3 = b12[col];
    float attAcc = 0.f, uvAcc = 0.f;
    float Mv = -INFINITY, Sv = 0.f;
    __syncthreads();
    int mBeg = seg * 256, mEnd = mBeg + 256;
    for (int m0 = mBeg; m0 < mEnd; m0 += 32) {
        if (t < 32) {
            int m = m0 + t;
            float s1 = sim1[m * 256 + n], r1 = rm1g[m];
            float s2 = sim2[m * 256 + n], r2 = rm2g[m];
            simf[t * 4 + 0] = s1 / (cm1 + 1e-6f);
            simf[t * 4 + 1] = s1 / (r1 + 1e-10f);
            simf[t * 4 + 2] = s2 / (cm2 + 1e-6f);
            simf[t * 4 + 3] = s2 / (r2 + 1e-10f);
        } else if (t >= 64 && t < 160) {
            int i = t - 64; int row = i / 3, c = i - row * 3;
            rfi3[i] = rfig[(m0 + row) * 3 + c];
        }
        __syncthreads();
        // layer 1 combine -> f16 H1 [row][k]
        for (int idx = t; idx < 4096; idx += 256) {
            int row = idx >> 7, k = idx & 127;
            int m = m0 + row;
            float v = base1n[k] + base2[m * 128 + k]
                    + simf[row * 4 + 0] * simw[0 * 128 + k]
                    + simf[row * 4 + 1] * simw[1 * 128 + k]
                    + simf[row * 4 + 2] * simw[2 * 128 + k]
                    + simf[row * 4 + 3] * simw[3 * 128 + k];
            H1h[row * 136 + k] = (f16)fmaxf(v, 0.f);
        }
        __syncthreads();
        // layer 2: two 16-row tiles x this wave's 16 cols, K=128 via 4 MFMAs each
        {
            f32x4 a0 = {bias2, bias2, bias2, bias2};
            f32x4 a1 = a0;
            for (int s = 0; s < 4; s++) {
                f16x8 f0 = *(const f16x8*)&H1h[l16 * 136 + s * 32 + q * 8];
                f16x8 f1 = *(const f16x8*)&H1h[(16 + l16) * 136 + s * 32 + q * 8];
                a0 = __builtin_amdgcn_mfma_f32_16x16x32_f16(f0, B2f[s], a0, 0, 0, 0);
                a1 = __builtin_amdgcn_mfma_f32_16x16x32_f16(f1, B2f[s], a1, 0, 0, 0);
            }
            // C layout: row = q*4+reg, col = l16 (within tile)
            for (int r = 0; r < 4; r++) {
                H2h[(q * 4 + r) * 72 + col]      = (f16)fmaxf(a0[r], 0.f);
                H2h[(16 + q * 4 + r) * 72 + col] = (f16)fmaxf(a1[r], 0.f);
            }
        }
        __syncthreads();
        // layer 3: K=64 via 2 MFMAs per row tile
        {
            f32x4 c0 = {bias3, bias3, bias3, bias3};
            f32x4 c1 = c0;
            for (int s = 0; s < 2; s++) {
                f16x8 f0 = *(const f16x8*)&H2h[l16 * 72 + s * 32 + q * 8];
                f16x8 f1 = *(const f16x8*)&H2h[(16 + l16) * 72 + s * 32 + q * 8];
                c0 = __builtin_amdgcn_mfma_f32_16x16x32_f16(f0, B3f[s], c0, 0, 0, 0);
                c1 = __builtin_amdgcn_mfma_f32_16x16x32_f16(f1, B3f[s], c1, 0, 0, 0);
            }
            for (int r = 0; r < 4; r++) {
                H3[(q * 4 + r) * 68 + col]      = fmaxf(c0[r], 0.f);
                H3[(16 + q * 4 + r) * 68 + col] = fmaxf(c1[r], 0.f);
            }
        }
        __syncthreads();
        if (t < 32) {
            float mx = -INFINITY;
            for (int c = 0; c < 64; c++) mx = fmaxf(mx, H3[t * 68 + c]);
            rm[t] = mx;
        }
        __syncthreads();
        float tmax = -INFINITY;
        for (int r = 0; r < 32; r++) tmax = fmaxf(tmax, rm[r]);
        float newM = fmaxf(Mv, tmax);
        float rescale = expf(Mv - newM);
        if (t < 32) ew[t] = expf(rm[t] - newM);
        Mv = newM;
        __syncthreads();
        float sumew = 0.f;
        for (int r = 0; r < 32; r++) sumew += ew[r];
        Sv = Sv * rescale + sumew;
        if (t < 64) {
            float acc = 0.f;
            for (int r = 0; r < 32; r++) acc += ew[r] * H3[r * 68 + t];
            attAcc = attAcc * rescale + acc;
        } else if (t < 67) {
            int c = t - 64; float acc = 0.f;
            for (int r = 0; r < 32; r++) acc += ew[r] * rfi3[r * 3 + c];
            uvAcc = uvAcc * rescale + acc;
        }
        __syncthreads();
    }
    int p = n * 4 + seg;
    if (t == 0) { ws[WS_PM + p] = Mv; ws[WS_PS + p] = Sv; }
    if (t < 64) ws[WS_PATT + p * 64 + t] = attAcc;
    else if (t < 67) ws[WS_PUV + p * 3 + (t - 64)] = uvAcc;
}

// ---------------- merge the 4 m-segments (exact flash-style combine) ----------------
__global__ __launch_bounds__(128) void combine_kernel(float* ws) {
    int n = blockIdx.x, t = threadIdx.x;
    float pm[4], e[4];
    float M = -INFINITY;
    for (int s = 0; s < 4; s++) { pm[s] = ws[WS_PM + n * 4 + s]; M = fmaxf(M, pm[s]); }
    float S = 0.f;
    for (int s = 0; s < 4; s++) { e[s] = expf(pm[s] - M); S += ws[WS_PS + n * 4 + s] * e[s]; }
    if (t < 64) {
        float acc = 0.f;
        for (int s = 0; s < 4; s++) acc += ws[WS_PATT + (n * 4 + s) * 64 + t] * e[s];
        ws[WS_ATT + n * 64 + t] = acc / S;
    } else if (t < 67) {
        int c = t - 64; float acc = 0.f;
        for (int s = 0; s < 4; s++) acc += ws[WS_PUV + (n * 4 + s) * 3 + c] * e[s];
        ws[WS_UV + n * 3 + c] = acc / S;
    }
}

// ---------------- head MLP -> weights (d_out), w_in ----------------
__global__ __launch_bounds__(128) void head_kernel(float* ws,
        const float* wm0, const float* bm0, const float* wm1, const float* bm1,
        const float* wm2, const float* bm2, float* out) {
    __shared__ float av[64], ha[64], hb[128], lg[2];
    int n = blockIdx.x, t = threadIdx.x;
    if (t < 64) av[t] = ws[WS_ATT + n * 64 + t];
    __syncthreads();
    if (t < 64) {
        float acc = bm0[t];
        for (int i = 0; i < 64; i++) acc += av[i] * wm0[i * 64 + t];
        ha[t] = fmaxf(acc, 0.f);
    }
    __syncthreads();
    {
        float acc = bm1[t];
        for (int i = 0; i < 64; i++) acc += ha[i] * wm1[i * 128 + t];
        hb[t] = fmaxf(acc, 0.f);
    }
    __syncthreads();
    if (t < 2) {
        float acc = bm2[t];
        for (int i = 0; i < 128; i++) acc += hb[i] * wm2[i * 2 + t];
        lg[t] = acc;
    }
    __syncthreads();
    if (t == 0) {
        float l0 = lg[0], l1 = lg[1];
        float mx = fmaxf(l0, l1);
        float e0 = expf(l0 - mx), e1 = expf(l1 - mx);
        float s = e0 + e1;
        out[12 + n * 2 + 0] = e0 / s;
        out[12 + n * 2 + 1] = e1 / s;
        ws[WS_WIN + n] = (e1 > e0) ? 1.f : 0.f;
    }
}

// ---------------- weighted PnP (Kabsch with 3x3 SVD, double) ----------------
__device__ void compute_rt(const double Hm[9], const double sc[3], const double dc[3],
                           float* out) {
    double Hd[3][3] = {{Hm[0], Hm[1], Hm[2]}, {Hm[3], Hm[4], Hm[5]}, {Hm[6], Hm[7], Hm[8]}};
    double A[3][3], V[3][3] = {{1, 0, 0}, {0, 1, 0}, {0, 0, 1}};
    for (int i = 0; i < 3; i++)
        for (int j = 0; j < 3; j++) {
            double s = 0;
            for (int k = 0; k < 3; k++) s += Hd[k][i] * Hd[k][j];
            A[i][j] = s;
        }
    for (int sweep = 0; sweep < 50; sweep++) {
        double off = fabs(A[0][1]) + fabs(A[0][2]) + fabs(A[1][2]);
        if (off < 1e-28) break;
        const int PQ[3][2] = {{0, 1}, {0, 2}, {1, 2}};
        for (int pp = 0; pp < 3; pp++) {
            int p = PQ[pp][0], q = PQ[pp][1];
            double apq = A[p][q];
            if (fabs(apq) < 1e-300) continue;
            double tau = (A[q][q] - A[p][p]) / (2.0 * apq);
            double tt = (tau >= 0.0 ? 1.0 : -1.0) / (fabs(tau) + sqrt(1.0 + tau * tau));
            double c = 1.0 / sqrt(1.0 + tt * tt), s = tt * c;
            for (int k = 0; k < 3; k++) {
                double akp = A[k][p], akq = A[k][q];
                A[k][p] = c * akp - s * akq; A[k][q] = s * akp + c * akq;
            }
            for (int k = 0; k < 3; k++) {
                double apk = A[p][k], aqk = A[q][k];
                A[p][k] = c * apk - s * aqk; A[q][k] = s * apk + c * aqk;
            }
            for (int k = 0; k < 3; k++) {
                double vkp = V[k][p], vkq = V[k][q];
                V[k][p] = c * vkp - s * vkq; V[k][q] = s * vkp + c * vkq;
            }
        }
    }
    double lam[3] = {A[0][0], A[1][1], A[2][2]};
    int o0 = 0, o1 = 1, o2 = 2;
    if (lam[o0] < lam[o1]) { int tp = o0; o0 = o1; o1 = tp; }
    if (lam[o0] < lam[o2]) { int tp = o0; o0 = o2; o2 = tp; }
    if (lam[o1] < lam[o2]) { int tp = o1; o1 = o2; o2 = tp; }
    int ord[3] = {o0, o1, o2};
    double v[3][3], u[3][3], R[3][3];
    for (int k = 0; k < 3; k++)
        for (int i = 0; i < 3; i++) v[k][i] = V[i][ord[k]];
    double sv0 = sqrt(fmax(lam[o0], 0.0));
    if (!(sv0 > 1e-150)) {
        for (int i = 0; i < 3; i++)
            for (int j = 0; j < 3; j++) R[i][j] = (i == j) ? 1.0 : 0.0;
    } else {
        double nn[3];
        for (int k = 0; k < 3; k++) {
            for (int i = 0; i < 3; i++)
                u[k][i] = Hd[i][0] * v[k][0] + Hd[i][1] * v[k][1] + Hd[i][2] * v[k][2];
            nn[k] = sqrt(u[k][0] * u[k][0] + u[k][1] * u[k][1] + u[k][2] * u[k][2]);
        }
        for (int i = 0; i < 3; i++) u[0][i] /= nn[0];
        if (nn[1] > 1e-12 * nn[0]) {
            for (int i = 0; i < 3; i++) u[1][i] /= nn[1];
        } else {
            int e = (fabs(u[0][0]) <= fabs(u[0][1]) && fabs(u[0][0]) <= fabs(u[0][2])) ? 0
                    : ((fabs(u[0][1]) <= fabs(u[0][2])) ? 1 : 2);
            double ev[3] = {0, 0, 0}; ev[e] = 1.0;
            double d0 = ev[0] * u[0][0] + ev[1] * u[0][1] + ev[2] * u[0][2];
            double w1v[3], wn2 = 0;
            for (int i = 0; i < 3; i++) { w1v[i] = ev[i] - d0 * u[0][i]; wn2 += w1v[i] * w1v[i]; }
            wn2 = sqrt(wn2);
            for (int i = 0; i < 3; i++) u[1][i] = w1v[i] / wn2;
        }
        if (nn[2] > 1e-10 * nn[0]) {
            for (int i = 0; i < 3; i++) u[2][i] /= nn[2];
        } else {
            u[2][0] = u[0][1] * u[1][2] - u[0][2] * u[1][1];
            u[2][1] = u[0][2] * u[1][0] - u[0][0] * u[1][2];
            u[2][2] = u[0][0] * u[1][1] - u[0][1] * u[1][0];
        }
        double cr[3] = {u[1][1] * u[2][2] - u[1][2] * u[2][1],
                        u[1][2] * u[2][0] - u[1][0] * u[2][2],
                        u[1][0] * u[2][1] - u[1][1] * u[2][0]};
        double detU = u[0][0] * cr[0] + u[0][1] * cr[1] + u[0][2] * cr[2];
        double cv[3] = {v[1][1] * v[2][2] - v[1][2] * v[2][1],
                        v[1][2] * v[2][0] - v[1][0] * v[2][2],
                        v[1][0] * v[2][1] - v[1][1] * v[2][0]};
        double detV = v[0][0] * cv[0] + v[0][1] * cv[1] + v[0][2] * cv[2];
        double dsign = detU * detV;
        for (int i = 0; i < 3; i++)
            for (int j = 0; j < 3; j++)
                R[i][j] = v[0][i] * u[0][j] + v[1][i] * u[1][j] + dsign * v[2][i] * u[2][j];
    }
    for (int i = 0; i < 3; i++) {
        double ti = dc[i] - (R[i][0] * sc[0] + R[i][1] * sc[1] + R[i][2] * sc[2]);
        out[9 + i] = (float)ti;
        for (int j = 0; j < 3; j++) out[i * 3 + j] = (float)R[i][j];
    }
}

__global__ __launch_bounds__(256) void pnp_kernel(float* ws, float* out) {
    __shared__ double red[256];
    int t = threadIdx.x;
    double w = (double)ws[WS_WIN + t];
    double x0 = ws[WS_XYZ + t * 3 + 0];
    double x1 = ws[WS_XYZ + t * 3 + 1];
    double x2 = ws[WS_XYZ + t * 3 + 2];
    double z = x2;
    double dd0 = (double)ws[WS_UV + t * 3 + 0] * z;
    double dd1 = (double)ws[WS_UV + t * 3 + 1] * z;
    double dd2 = z;
    auto reduce = [&](double v) -> double {
        red[t] = v; __syncthreads();
        for (int s = 128; s > 0; s >>= 1) {
            if (t < s) red[t] += red[t + s];
            __syncthreads();
        }
        double r = red[0]; __syncthreads();
        return r;
    };
    double wsum = reduce(w);
    double sx0 = reduce(w * x0), sx1 = reduce(w * x1), sx2 = reduce(w * x2);
    double sd0 = reduce(w * dd0), sd1 = reduce(w * dd1), sd2 = reduce(w * dd2);
    double inv = 1.0 / (wsum + 1e-8);
    double sc[3] = {sx0 * inv, sx1 * inv, sx2 * inv};
    double dc[3] = {sd0 * inv, sd1 * inv, sd2 * inv};
    double wn = w * inv;
    double a0 = x0 - sc[0], a1 = x1 - sc[1], a2 = x2 - sc[2];
    double b0 = dd0 - dc[0], b1 = dd1 - dc[1], b2 = dd2 - dc[2];
    double Hm[9];
    Hm[0] = reduce(wn * a0 * b0); Hm[1] = reduce(wn * a0 * b1); Hm[2] = reduce(wn * a0 * b2);
    Hm[3] = reduce(wn * a1 * b0); Hm[4] = reduce(wn * a1 * b1); Hm[5] = reduce(wn * a1 * b2);
    Hm[6] = reduce(wn * a2 * b0); Hm[7] = reduce(wn * a2 * b1); Hm[8] = reduce(wn * a2 * b2);
    if (t == 0) compute_rt(Hm, sc, dc, out);
}

// ---------------- launch ----------------
extern "C" void kernel_launch(void* const* d_in, const int* in_sizes, int n_in,
                              void* d_out, int out_size, void* d_ws, size_t ws_size,
                              hipStream_t stream) {
    float* ws = (float*)d_ws;
    const float* wxyz = (const float*)d_in[0];
    const float* wpts = (const float*)d_in[1];
    const float* RF3  = (const float*)d_in[2];
    const float* RFI  = (const float*)d_in[3];
    const float* lz   = (const float*)d_in[4];
    const float* w2_0 = (const float*)d_in[5];  const float* b2_0 = (const float*)d_in[6];
    const float* w2_1 = (const float*)d_in[7];  const float* b2_1 = (const float*)d_in[8];
    const float* w2_2 = (const float*)d_in[9];  const float* b2_2 = (const float*)d_in[10];
    const float* w3_0 = (const float*)d_in[11]; const float* b3_0 = (const float*)d_in[12];
    const float* w3_1 = (const float*)d_in[13]; const float* b3_1 = (const float*)d_in[14];
    const float* w3_2 = (const float*)d_in[15]; const float* b3_2 = (const float*)d_in[16];
    const float* w1_0 = (const float*)d_in[17]; const float* b1_0 = (const float*)d_in[18];
    const float* w1_1 = (const float*)d_in[19]; const float* b1_1 = (const float*)d_in[20];
    const float* w1_2 = (const float*)d_in[21]; const float* b1_2 = (const float*)d_in[22];
    const float* wm_0 = (const float*)d_in[23]; const float* bm_0 = (const float*)d_in[24];
    const float* wm_1 = (const float*)d_in[25]; const float* bm_1 = (const float*)d_in[26];
    const float* wm_2 = (const float*)d_in[27]; const float* bm_2 = (const float*)d_in[28];
    float* out = (float*)d_out;

    prep_kernel<<<272, 256, 0, stream>>>(ws, wxyz, lz, RF3, RFI);
    prepw_kernel<<<48, 256, 0, stream>>>(ws, w1_1, w1_2);
    rownorm_kernel<<<256, 64, 0, stream>>>(wpts, ws + WS_SN);
    rownorm_kernel<<<1024, 64, 0, stream>>>(ws + WS_RF, ws + WS_DN);
    sim_kernel<<<1024, 256, 0, stream>>>(ws + WS_DN, ws + WS_SN, ws + WS_SIM1, ws + WS_RM1);
    colmax_kernel<<<256, 256, 0, stream>>>(ws + WS_SIM1, ws + WS_CM1);
    knn_kernel<<<256, 256, 0, stream>>>(ws);
    mlp2_kernel<<<256, 256, 0, stream>>>(ws, wpts, w2_0, b2_0, w2_1, b2_1, w2_2, b2_2);
    g3_kernel<<<1025, 64, 0, stream>>>(ws, w3_0, b3_0);
    mlp3_kernel<<<256, 256, 0, stream>>>(ws, w3_1, b3_1, w3_2, b3_2);
    rownorm_kernel<<<256, 64, 0, stream>>>(ws + WS_PCF, ws + WS_PCN);
    rownorm_kernel<<<1024, 64, 0, stream>>>(ws + WS_IMGF, ws + WS_IMGN);
    sim_kernel<<<1024, 256, 0, stream>>>(ws + WS_IMGN, ws + WS_PCN, ws + WS_SIM2, ws + WS_RM2);
    colmax_kernel<<<256, 256, 0, stream>>>(ws + WS_SIM2, ws + WS_CM2);
    base1_kernel<<<256, 128, 0, stream>>>(ws, wpts, w1_0, b1_0);
    base2_kernel<<<1024, 128, 0, stream>>>(ws, w1_0);
    mlp1_kernel<<<dim3(4, 256), 256, 0, stream>>>(ws, w1_0, b1_1, b1_2);
    combine_kernel<<<256, 128, 0, stream>>>(ws);
    head_kernel<<<256, 128, 0, stream>>>(ws, wm_0, bm_0, wm_1, bm_1, wm_2, bm_2, out);
    pnp_kernel<<<1, 256, 0, stream>>>(ws, out);
}

// Round 7
// 282.275 us; speedup vs baseline: 2.4335x; 1.0287x over previous
//
#include <hip/hip_runtime.h>
#include <math.h>

// Problem constants
// B=1, N=256, H=32, W=32, M=1024, C_LIDAR=C_RGB=64, K=16, S=3, MLP3=[128,64,64]

typedef _Float16 f16;
typedef __attribute__((ext_vector_type(4))) _Float16 f16x4;
typedef __attribute__((ext_vector_type(8))) _Float16 f16x8;
typedef __attribute__((ext_vector_type(4))) float f32x4;

// ---------------- workspace layout (float offsets) ----------------
constexpr int WS_XYZ  = 0;                  // 256*3
constexpr int WS_RF   = 768;                // 1024*64
constexpr int WS_RFI  = WS_RF   + 65536;    // 1024*3
constexpr int WS_SN   = WS_RFI  + 3072;     // 256*64
constexpr int WS_DN   = WS_SN   + 16384;    // 1024*64
constexpr int WS_SIM1 = WS_DN   + 65536;    // 1024*256 sim[m][n]
constexpr int WS_RM1  = WS_SIM1 + 262144;   // 1024 max over n
constexpr int WS_CM1  = WS_RM1  + 1024;     // 256  max over m
constexpr int WS_PCF  = WS_CM1  + 256;      // 256*64
constexpr int WS_IMGF = WS_PCF  + 16384;    // 1024*64
constexpr int WS_PCN  = WS_IMGF + 65536;    // 256*64
constexpr int WS_IMGN = WS_PCN  + 16384;    // 1024*64
constexpr int WS_SIM2 = WS_IMGN + 65536;    // 1024*256
constexpr int WS_RM2  = WS_SIM2 + 262144;   // 1024
constexpr int WS_CM2  = WS_RM2  + 1024;     // 256
constexpr int WS_B1   = WS_CM2  + 256;      // 256*128
constexpr int WS_B2   = WS_B1   + 32768;    // 1024*128
constexpr int WS_ATT  = WS_B2   + 131072;   // 256*64 (unused, layout keep)
constexpr int WS_UV   = WS_ATT  + 16384;    // 256*3
constexpr int WS_WIN  = WS_UV   + 768;      // 256
constexpr int WS_KNN  = WS_WIN  + 256;      // 256*16 ints
constexpr int WS_PM   = WS_KNN  + 4096;     // 256*4 partial max
constexpr int WS_PS   = WS_PM   + 1024;     // 256*4 partial sum
constexpr int WS_PATT = WS_PS   + 1024;     // 256*4*64 partial att
constexpr int WS_PUV  = WS_PATT + 65536;    // 256*4*3 partial uv
constexpr int WS_W11T = WS_PUV  + 3072;     // 4096 floats = 8192 f16 (w1_1^T [col][k])
constexpr int WS_W12T = WS_W11T + 4096;     // 2048 floats = 4096 f16 (w1_2^T [col][k])
constexpr int WS_G3   = WS_W12T + 2048;     // 1025*64 (MLP3 layer-1 per-pixel)

// ---------------- prep: transposes + f16 weight transposes ----------------
__global__ __launch_bounds__(256) void prep_kernel(float* ws, const float* wxyz,
                                                   const float* lz, const float* RF3,
                                                   const float* RFI, const float* w11,
                                                   const float* w12) {
    int i = blockIdx.x * 256 + threadIdx.x;
    if (i < 768) {
        int n = i / 3;
        ws[WS_XYZ + i] = wxyz[i] * lz[n];
    } else if (i < 768 + 65536) {
        int j = i - 768; int mm = j >> 6, c = j & 63;
        ws[WS_RF + j] = RF3[c * 1024 + mm];
    } else if (i < 768 + 65536 + 3072) {
        int j = i - (768 + 65536); int mm = j / 3, c = j - mm * 3;
        ws[WS_RFI + j] = RFI[c * 1024 + mm];
    } else if (i < 69376 + 8192) {
        int j = i - 69376; int col = j >> 7, k = j & 127;
        ((f16*)(ws + WS_W11T))[col * 128 + k] = (f16)w11[k * 64 + col];
    } else if (i < 69376 + 12288) {
        int j = i - (69376 + 8192); int col = j >> 6, k = j & 63;
        ((f16*)(ws + WS_W12T))[col * 64 + k] = (f16)w12[k * 64 + col];
    }
}

// ---------------- fused double row L2-normalize (64 cols) ----------------
__global__ __launch_bounds__(64) void rownorm2_kernel(const float* sA, float* dA,
                                                      const float* sB, float* dB) {
    int b = blockIdx.x, t = threadIdx.x;
    const float* src; float* dst; int r;
    if (b < 256) { src = sA; dst = dA; r = b; }
    else         { src = sB; dst = dB; r = b - 256; }
    float v = src[r * 64 + t];
    float s = v * v;
    for (int o = 32; o > 0; o >>= 1) s += __shfl_down(s, o);
    s = __shfl(s, 0);
    float nrm = sqrtf(s);
    dst[r * 64 + t] = v / fmaxf(nrm, 1e-12f);
}

// ---------------- sim[m][n] = d[m] . s[n]; rowmax over n ----------------
__global__ __launch_bounds__(256) void sim_kernel(const float* dn, const float* sn,
                                                  float* sim, float* rmax) {
    __shared__ __align__(16) float dv[64];
    __shared__ float red[256];
    int m = blockIdx.x, t = threadIdx.x;
    if (t < 64) dv[t] = dn[m * 64 + t];
    __syncthreads();
    float acc = 0.f;
    const float4* sp = (const float4*)(sn + t * 64);
    const float4* dp = (const float4*)dv;
    for (int i = 0; i < 16; i++) {
        float4 s4 = sp[i], d4 = dp[i];
        acc += s4.x * d4.x + s4.y * d4.y + s4.z * d4.z + s4.w * d4.w;
    }
    sim[m * 256 + t] = acc;
    red[t] = acc; __syncthreads();
    for (int s = 128; s > 0; s >>= 1) {
        if (t < s) red[t] = fmaxf(red[t], red[t + s]);
        __syncthreads();
    }
    if (t == 0) rmax[m] = red[0];
}

// ---------------- colmax over m per n ----------------
__global__ __launch_bounds__(256) void colmax_kernel(const float* sim, float* cmax) {
    __shared__ float red[256];
    int n = blockIdx.x, t = threadIdx.x;
    float mx = -INFINITY;
    for (int m = t; m < 1024; m += 256) mx = fmaxf(mx, sim[m * 256 + n]);
    red[t] = mx; __syncthreads();
    for (int s = 128; s > 0; s >>= 1) {
        if (t < s) red[t] = fmaxf(red[t], red[t + s]);
        __syncthreads();
    }
    if (t == 0) cmax[n] = red[0];
}

// ---------------- 16-NN per point (R2-exact LDS tree version) ----------------
__global__ __launch_bounds__(256) void knn_kernel(float* ws) {
    const float* xyz = ws + WS_XYZ;
    int* knn = (int*)(ws + WS_KNN);
    __shared__ float px[256], py[256], pz[256], d2[256];
    __shared__ float rv[256];
    __shared__ int   ri[256];
    int n = blockIdx.x, t = threadIdx.x;
    px[t] = xyz[t * 3 + 0]; py[t] = xyz[t * 3 + 1]; pz[t] = xyz[t * 3 + 2];
    __syncthreads();
    float dx = px[t] - px[n], dy = py[t] - py[n], dz = pz[t] - pz[n];
    d2[t] = dx * dx + dy * dy + dz * dz;
    __syncthreads();
    for (int k = 0; k < 16; k++) {
        rv[t] = d2[t]; ri[t] = t;
        __syncthreads();
        for (int s = 128; s > 0; s >>= 1) {
            if (t < s) {
                float v2 = rv[t + s]; int i2 = ri[t + s];
                if (v2 < rv[t] || (v2 == rv[t] && i2 < ri[t])) { rv[t] = v2; ri[t] = i2; }
            }
            __syncthreads();
        }
        if (t == 0) { knn[n * 16 + k] = ri[0]; d2[ri[0]] = INFINITY; }
        __syncthreads();
    }
}

// ---------------- point branch: MLP2 over 16 neighbors -> pc_feats ----------------
__global__ __launch_bounds__(256) void mlp2_kernel(float* ws, const float* wpts,
        const float* w0, const float* b0, const float* w1, const float* b1,
        const float* w2, const float* b2) {
    __shared__ float wA[68 * 64], wB[64 * 64], wC[64 * 64];
    __shared__ float bA[64], bB[64], bC[64];
    __shared__ float x[16 * 68], hA[16 * 68], hB[16 * 68];
    __shared__ int   kn[16];
    __shared__ float wv[16], wts[16];
    int n = blockIdx.x, t = threadIdx.x;
    const float* xyz = ws + WS_XYZ;
    const int* knn = (const int*)(ws + WS_KNN);
    for (int i = t; i < 68 * 64; i += 256) wA[i] = w0[i];
    for (int i = t; i < 64 * 64; i += 256) { wB[i] = w1[i]; wC[i] = w2[i]; }
    if (t < 64) { bA[t] = b0[t]; bB[t] = b1[t]; bC[t] = b2[t]; }
    if (t < 16) kn[t] = knn[n * 16 + t];
    __syncthreads();
    for (int i = t; i < 1024; i += 256) {
        int k = i >> 6, c = i & 63;
        x[k * 68 + c] = wpts[kn[k] * 64 + c];
    }
    if (t < 16) {
        int i = kn[t];
        float dx = xyz[i * 3 + 0] - xyz[n * 3 + 0];
        float dy = xyz[i * 3 + 1] - xyz[n * 3 + 1];
        float dz = xyz[i * 3 + 2] - xyz[n * 3 + 2];
        x[t * 68 + 64] = dx; x[t * 68 + 65] = dy; x[t * 68 + 66] = dz;
        x[t * 68 + 67] = sqrtf(dx * dx + dy * dy + dz * dz);
    }
    __syncthreads();
    for (int o = t; o < 1024; o += 256) {
        int k = o >> 6, j = o & 63; float acc = bA[j];
        for (int i = 0; i < 68; i++) acc += x[k * 68 + i] * wA[i * 64 + j];
        hA[k * 68 + j] = fmaxf(acc, 0.f);
    }
    __syncthreads();
    for (int o = t; o < 1024; o += 256) {
        int k = o >> 6, j = o & 63; float acc = bB[j];
        for (int i = 0; i < 64; i++) acc += hA[k * 68 + i] * wB[i * 64 + j];
        hB[k * 68 + j] = fmaxf(acc, 0.f);
    }
    __syncthreads();
    for (int o = t; o < 1024; o += 256) {
        int k = o >> 6, j = o & 63; float acc = bC[j];
        for (int i = 0; i < 64; i++) acc += hB[k * 68 + i] * wC[i * 64 + j];
        hA[k * 68 + j] = fmaxf(acc, 0.f);
    }
    __syncthreads();
    if (t < 16) {
        float mx = -INFINITY;
        for (int j = 0; j < 64; j++) mx = fmaxf(mx, hA[t * 68 + j]);
        wv[t] = mx;
    }
    __syncthreads();
    if (t < 16) {
        float mx = -INFINITY;
        for (int k = 0; k < 16; k++) mx = fmaxf(mx, wv[k]);
        float sum = 0.f;
        for (int k = 0; k < 16; k++) sum += expf(wv[k] - mx);
        wts[t] = expf(wv[t] - mx) / sum;
    }
    __syncthreads();
    if (t < 64) {
        float acc = 0.f;
        for (int k = 0; k < 16; k++) acc += wts[k] * x[k * 68 + t];
        ws[WS_PCF + n * 64 + t] = acc;
    }
}

// ---------------- MLP3 layer-1 per-pixel GEMV ----------------
__global__ __launch_bounds__(64) void g3_kernel(float* ws, const float* w0, const float* b0) {
    int m = blockIdx.x, j = threadIdx.x;
    float acc = b0[j];
    if (m < 1024) {
        for (int i = 0; i < 3; i++)  acc += ws[WS_RFI + m * 3 + i] * w0[i * 64 + j];
        for (int c = 0; c < 64; c++) acc += ws[WS_RF + m * 64 + c] * w0[(3 + c) * 64 + j];
    }
    ws[WS_G3 + m * 64 + j] = fmaxf(acc, 0.f);
}

// ---------------- image branch: layers 2/3 over gathered G -> img_feats ----------
__global__ __launch_bounds__(256) void mlp3_kernel(float* ws,
        const float* w1, const float* b1, const float* w2, const float* b2) {
    __shared__ float wB[64 * 64], wC[64 * 64];
    __shared__ float bB[64], bC[64];
    __shared__ float x1[36 * 68], h2[36 * 68];
    __shared__ float h3v[36], iw9[36];
    int m0 = blockIdx.x * 4, t = threadIdx.x;
    const float* G = ws + WS_G3;
    const float* rf = ws + WS_RF;
    for (int i = t; i < 4096; i += 256) { wB[i] = w1[i]; wC[i] = w2[i]; }
    if (t < 64) { bB[t] = b1[t]; bC[t] = b2[t]; }
    for (int i = t; i < 36 * 64; i += 256) {
        int row = i >> 6, c = i & 63;
        int mi = row / 9, kk = row - mi * 9;
        int m = m0 + mi; int y = m >> 5, x = m & 31;
        int dy = kk / 3 - 1, dx = kk % 3 - 1;
        int ny = y + dy, nx = x + dx;
        bool val = (ny >= 0 && ny < 32 && nx >= 0 && nx < 32);
        int idx = val ? (ny * 32 + nx) : 1024;
        x1[row * 68 + c] = G[idx * 64 + c];
    }
    __syncthreads();
    for (int o = t; o < 36 * 64; o += 256) {
        int row = o >> 6, c = o & 63; float acc = bB[c];
        for (int i = 0; i < 64; i++) acc += x1[row * 68 + i] * wB[i * 64 + c];
        h2[row * 68 + c] = fmaxf(acc, 0.f);
    }
    __syncthreads();
    for (int o = t; o < 36 * 64; o += 256) {
        int row = o >> 6, c = o & 63; float acc = bC[c];
        for (int i = 0; i < 64; i++) acc += h2[row * 68 + i] * wC[i * 64 + c];
        x1[row * 68 + c] = fmaxf(acc, 0.f);
    }
    __syncthreads();
    if (t < 36) {
        float mx = -INFINITY;
        for (int c = 0; c < 64; c++) mx = fmaxf(mx, x1[t * 68 + c]);
        h3v[t] = mx;
    }
    __syncthreads();
    if (t < 36) {
        int mi = t / 9;
        float mx = -INFINITY;
        for (int k = 0; k < 9; k++) mx = fmaxf(mx, h3v[mi * 9 + k]);
        float sum = 0.f;
        for (int k = 0; k < 9; k++) sum += expf(h3v[mi * 9 + k] - mx);
        iw9[t] = expf(h3v[t] - mx) / sum;
    }
    __syncthreads();
    {
        int mi = t >> 6, c = t & 63;
        int m = m0 + mi; int y = m >> 5, x = m & 31;
        float acc = 0.f;
        for (int kk = 0; kk < 9; kk++) {
            int dy = kk / 3 - 1, dx = kk % 3 - 1;
            int ny = y + dy, nx = x + dx;
            bool val = (ny >= 0 && ny < 32 && nx >= 0 && nx < 32);
            if (val) acc += iw9[mi * 9 + kk] * rf[(ny * 32 + nx) * 64 + c];
        }
        ws[WS_IMGF + m * 64 + c] = acc;
    }
}

// ---------------- fused MLP1 layer-1 decomposition (base1 + base2) ----------------
__global__ __launch_bounds__(128) void base12_kernel(float* ws, const float* wpts,
                                                     const float* w10, const float* b10) {
    int b = blockIdx.x, j = threadIdx.x;
    if (b < 256) {
        int n = b;
        float acc = b10[j];
        for (int i = 0; i < 3; i++)  acc += ws[WS_XYZ + n * 3 + i] * w10[i * 128 + j];
        for (int c = 0; c < 64; c++) acc += wpts[n * 64 + c] * w10[(6 + c) * 128 + j];
        ws[WS_B1 + n * 128 + j] = acc;
    } else {
        int m = b - 256;
        float acc = 0.f;
        for (int i = 0; i < 3; i++)  acc += ws[WS_RFI + m * 3 + i] * w10[(3 + i) * 128 + j];
        for (int c = 0; c < 64; c++) acc += ws[WS_RF + m * 64 + c] * w10[(70 + c) * 128 + j];
        ws[WS_B2 + m * 128 + j] = acc;
    }
}

// ---------------- main fused MLP1 (R2-exact: 32-row chunks, MFMA f16) -----------
__global__ __launch_bounds__(256) void mlp1_kernel(float* ws, const float* w10,
        const float* b11, const float* b12) {
    __shared__ __align__(16) f16 H1h[32 * 136];   // [row][k], stride 136 halves
    __shared__ __align__(16) f16 H2h[32 * 72];    // [row][k], stride 72 halves
    __shared__ __align__(16) float H3[32 * 68];   // [row][col]
    __shared__ float base1n[128];
    __shared__ float simw[4 * 128];
    __shared__ float simf[32 * 4];
    __shared__ float rfi3[32 * 3];
    __shared__ float rm[32], ew[32];
    int n = blockIdx.y, seg = blockIdx.x, t = threadIdx.x;
    int wave = t >> 6, lane = t & 63, q = lane >> 4, l16 = lane & 15;
    int col = wave * 16 + l16;
    const float* sim1 = ws + WS_SIM1;  const float* rm1g = ws + WS_RM1;
    const float* sim2 = ws + WS_SIM2;  const float* rm2g = ws + WS_RM2;
    const float* base2 = ws + WS_B2;   const float* rfig = ws + WS_RFI;
    const f16* w11t = (const f16*)(ws + WS_W11T);
    const f16* w12t = (const f16*)(ws + WS_W12T);
    float cm1 = ws[WS_CM1 + n], cm2 = ws[WS_CM2 + n];
    if (t < 128) base1n[t] = ws[WS_B1 + n * 128 + t];
    for (int i = t; i < 512; i += 256) simw[i] = w10[134 * 128 + i];
    f16x8 B2f[4], B3f[2];
    for (int s = 0; s < 4; s++) B2f[s] = *(const f16x8*)&w11t[col * 128 + s * 32 + q * 8];
    for (int s = 0; s < 2; s++) B3f[s] = *(const f16x8*)&w12t[col * 64 + s * 32 + q * 8];
    float bias2 = b11[col], bias3 = b12[col];
    float attAcc = 0.f, uvAcc = 0.f;
    float Mv = -INFINITY, Sv = 0.f;
    __syncthreads();
    int mBeg = seg * 256, mEnd = mBeg + 256;
    for (int m0 = mBeg; m0 < mEnd; m0 += 32) {
        if (t < 32) {
            int m = m0 + t;
            float s1 = sim1[m * 256 + n], r1 = rm1g[m];
            float s2 = sim2[m * 256 + n], r2 = rm2g[m];
            simf[t * 4 + 0] = s1 / (cm1 + 1e-6f);
            simf[t * 4 + 1] = s1 / (r1 + 1e-10f);
            simf[t * 4 + 2] = s2 / (cm2 + 1e-6f);
            simf[t * 4 + 3] = s2 / (r2 + 1e-10f);
        } else if (t >= 64 && t < 160) {
            int i = t - 64; int row = i / 3, c = i - row * 3;
            rfi3[i] = rfig[(m0 + row) * 3 + c];
        }
        __syncthreads();
        for (int idx = t; idx < 4096; idx += 256) {
            int row = idx >> 7, k = idx & 127;
            int m = m0 + row;
            float v = base1n[k] + base2[m * 128 + k]
                    + simf[row * 4 + 0] * simw[0 * 128 + k]
                    + simf[row * 4 + 1] * simw[1 * 128 + k]
                    + simf[row * 4 + 2] * simw[2 * 128 + k]
                    + simf[row * 4 + 3] * simw[3 * 128 + k];
            H1h[row * 136 + k] = (f16)fmaxf(v, 0.f);
        }
        __syncthreads();
        {
            f32x4 a0 = {bias2, bias2, bias2, bias2};
            f32x4 a1 = a0;
            for (int s = 0; s < 4; s++) {
                f16x8 f0 = *(const f16x8*)&H1h[l16 * 136 + s * 32 + q * 8];
                f16x8 f1 = *(const f16x8*)&H1h[(16 + l16) * 136 + s * 32 + q * 8];
                a0 = __builtin_amdgcn_mfma_f32_16x16x32_f16(f0, B2f[s], a0, 0, 0, 0);
                a1 = __builtin_amdgcn_mfma_f32_16x16x32_f16(f1, B2f[s], a1, 0, 0, 0);
            }
            for (int r = 0; r < 4; r++) {
                H2h[(q * 4 + r) * 72 + col]      = (f16)fmaxf(a0[r], 0.f);
                H2h[(16 + q * 4 + r) * 72 + col] = (f16)fmaxf(a1[r], 0.f);
            }
        }
        __syncthreads();
        {
            f32x4 c0 = {bias3, bias3, bias3, bias3};
            f32x4 c1 = c0;
            for (int s = 0; s < 2; s++) {
                f16x8 f0 = *(const f16x8*)&H2h[l16 * 72 + s * 32 + q * 8];
                f16x8 f1 = *(const f16x8*)&H2h[(16 + l16) * 72 + s * 32 + q * 8];
                c0 = __builtin_amdgcn_mfma_f32_16x16x32_f16(f0, B3f[s], c0, 0, 0, 0);
                c1 = __builtin_amdgcn_mfma_f32_16x16x32_f16(f1, B3f[s], c1, 0, 0, 0);
            }
            for (int r = 0; r < 4; r++) {
                H3[(q * 4 + r) * 68 + col]      = fmaxf(c0[r], 0.f);
                H3[(16 + q * 4 + r) * 68 + col] = fmaxf(c1[r], 0.f);
            }
        }
        __syncthreads();
        if (t < 32) {
            float mx = -INFINITY;
            for (int c = 0; c < 64; c++) mx = fmaxf(mx, H3[t * 68 + c]);
            rm[t] = mx;
        }
        __syncthreads();
        float tmax = -INFINITY;
        for (int r = 0; r < 32; r++) tmax = fmaxf(tmax, rm[r]);
        float newM = fmaxf(Mv, tmax);
        float rescale = expf(Mv - newM);
        if (t < 32) ew[t] = expf(rm[t] - newM);
        Mv = newM;
        __syncthreads();
        float sumew = 0.f;
        for (int r = 0; r < 32; r++) sumew += ew[r];
        Sv = Sv * rescale + sumew;
        if (t < 64) {
            float acc = 0.f;
            for (int r = 0; r < 32; r++) acc += ew[r] * H3[r * 68 + t];
            attAcc = attAcc * rescale + acc;
        } else if (t < 67) {
            int c = t - 64; float acc = 0.f;
            for (int r = 0; r < 32; r++) acc += ew[r] * rfi3[r * 3 + c];
            uvAcc = uvAcc * rescale + acc;
        }
        __syncthreads();
    }
    int p = n * 4 + seg;
    if (t == 0) { ws[WS_PM + p] = Mv; ws[WS_PS + p] = Sv; }
    if (t < 64) ws[WS_PATT + p * 64 + t] = attAcc;
    else if (t < 67) ws[WS_PUV + p * 3 + (t - 64)] = uvAcc;
}

// ---------------- fused combine + head MLP -> weights (d_out), w_in, uv ------------
__global__ __launch_bounds__(128) void combinehead_kernel(float* ws,
        const float* wm0, const float* bm0, const float* wm1, const float* bm1,
        const float* wm2, const float* bm2, float* out) {
    __shared__ float av[64], ha[64], hb[128], lg[2];
    int n = blockIdx.x, t = threadIdx.x;
    float pm[4], e[4];
    float M = -INFINITY;
    for (int s = 0; s < 4; s++) { pm[s] = ws[WS_PM + n * 4 + s]; M = fmaxf(M, pm[s]); }
    float S = 0.f;
    for (int s = 0; s < 4; s++) { e[s] = expf(pm[s] - M); S += ws[WS_PS + n * 4 + s] * e[s]; }
    if (t < 64) {
        float acc = 0.f;
        for (int s = 0; s < 4; s++) acc += ws[WS_PATT + (n * 4 + s) * 64 + t] * e[s];
        av[t] = acc / S;
    } else if (t < 67) {
        int c = t - 64; float acc = 0.f;
        for (int s = 0; s < 4; s++) acc += ws[WS_PUV + (n * 4 + s) * 3 + c] * e[s];
        ws[WS_UV + n * 3 + c] = acc / S;
    }
    __syncthreads();
    if (t < 64) {
        float acc = bm0[t];
        for (int i = 0; i < 64; i++) acc += av[i] * wm0[i * 64 + t];
        ha[t] = fmaxf(acc, 0.f);
    }
    __syncthreads();
    {
        float acc = bm1[t];
        for (int i = 0; i < 64; i++) acc += ha[i] * wm1[i * 128 + t];
        hb[t] = fmaxf(acc, 0.f);
    }
    __syncthreads();
    if (t < 2) {
        float acc = bm2[t];
        for (int i = 0; i < 128; i++) acc += hb[i] * wm2[i * 2 + t];
        lg[t] = acc;
    }
    __syncthreads();
    if (t == 0) {
        float l0 = lg[0], l1 = lg[1];
        float mx = fmaxf(l0, l1);
        float e0 = expf(l0 - mx), e1 = expf(l1 - mx);
        float s = e0 + e1;
        out[12 + n * 2 + 0] = e0 / s;
        out[12 + n * 2 + 1] = e1 / s;
        ws[WS_WIN + n] = (e1 > e0) ? 1.f : 0.f;
    }
}

// ---------------- weighted PnP (Kabsch with 3x3 SVD, double) ----------------
__device__ void compute_rt(const double Hm[9], const double sc[3], const double dc[3],
                           float* out) {
    double Hd[3][3] = {{Hm[0], Hm[1], Hm[2]}, {Hm[3], Hm[4], Hm[5]}, {Hm[6], Hm[7], Hm[8]}};
    double A[3][3], V[3][3] = {{1, 0, 0}, {0, 1, 0}, {0, 0, 1}};
    for (int i = 0; i < 3; i++)
        for (int j = 0; j < 3; j++) {
            double s = 0;
            for (int k = 0; k < 3; k++) s += Hd[k][i] * Hd[k][j];
            A[i][j] = s;
        }
    for (int sweep = 0; sweep < 50; sweep++) {
        double off = fabs(A[0][1]) + fabs(A[0][2]) + fabs(A[1][2]);
        if (off < 1e-28) break;
        const int PQ[3][2] = {{0, 1}, {0, 2}, {1, 2}};
        for (int pp = 0; pp < 3; pp++) {
            int p = PQ[pp][0], q = PQ[pp][1];
            double apq = A[p][q];
            if (fabs(apq) < 1e-300) continue;
            double tau = (A[q][q] - A[p][p]) / (2.0 * apq);
            double tt = (tau >= 0.0 ? 1.0 : -1.0) / (fabs(tau) + sqrt(1.0 + tau * tau));
            double c = 1.0 / sqrt(1.0 + tt * tt), s = tt * c;
            for (int k = 0; k < 3; k++) {
                double akp = A[k][p], akq = A[k][q];
                A[k][p] = c * akp - s * akq; A[k][q] = s * akp + c * akq;
            }
            for (int k = 0; k < 3; k++) {
                double apk = A[p][k], aqk = A[q][k];
                A[p][k] = c * apk - s * aqk; A[q][k] = s * apk + c * aqk;
            }
            for (int k = 0; k < 3; k++) {
                double vkp = V[k][p], vkq = V[k][q];
                V[k][p] = c * vkp - s * vkq; V[k][q] = s * vkp + c * vkq;
            }
        }
    }
    double lam[3] = {A[0][0], A[1][1], A[2][2]};
    int o0 = 0, o1 = 1, o2 = 2;
    if (lam[o0] < lam[o1]) { int tp = o0; o0 = o1; o1 = tp; }
    if (lam[o0] < lam[o2]) { int tp = o0; o0 = o2; o2 = tp; }
    if (lam[o1] < lam[o2]) { int tp = o1; o1 = o2; o2 = tp; }
    int ord[3] = {o0, o1, o2};
    double v[3][3], u[3][3], R[3][3];
    for (int k = 0; k < 3; k++)
        for (int i = 0; i < 3; i++) v[k][i] = V[i][ord[k]];
    double sv0 = sqrt(fmax(lam[o0], 0.0));
    if (!(sv0 > 1e-150)) {
        for (int i = 0; i < 3; i++)
            for (int j = 0; j < 3; j++) R[i][j] = (i == j) ? 1.0 : 0.0;
    } else {
        double nn[3];
        for (int k = 0; k < 3; k++) {
            for (int i = 0; i < 3; i++)
                u[k][i] = Hd[i][0] * v[k][0] + Hd[i][1] * v[k][1] + Hd[i][2] * v[k][2];
            nn[k] = sqrt(u[k][0] * u[k][0] + u[k][1] * u[k][1] + u[k][2] * u[k][2]);
        }
        for (int i = 0; i < 3; i++) u[0][i] /= nn[0];
        if (nn[1] > 1e-12 * nn[0]) {
            for (int i = 0; i < 3; i++) u[1][i] /= nn[1];
        } else {
            int e = (fabs(u[0][0]) <= fabs(u[0][1]) && fabs(u[0][0]) <= fabs(u[0][2])) ? 0
                    : ((fabs(u[0][1]) <= fabs(u[0][2])) ? 1 : 2);
            double ev[3] = {0, 0, 0}; ev[e] = 1.0;
            double d0 = ev[0] * u[0][0] + ev[1] * u[0][1] + ev[2] * u[0][2];
            double w1v[3], wn2 = 0;
            for (int i = 0; i < 3; i++) { w1v[i] = ev[i] - d0 * u[0][i]; wn2 += w1v[i] * w1v[i]; }
            wn2 = sqrt(wn2);
            for (int i = 0; i < 3; i++) u[1][i] = w1v[i] / wn2;
        }
        if (nn[2] > 1e-10 * nn[0]) {
            for (int i = 0; i < 3; i++) u[2][i] /= nn[2];
        } else {
            u[2][0] = u[0][1] * u[1][2] - u[0][2] * u[1][1];
            u[2][1] = u[0][2] * u[1][0] - u[0][0] * u[1][2];
            u[2][2] = u[0][0] * u[1][1] - u[0][1] * u[1][0];
        }
        double cr[3] = {u[1][1] * u[2][2] - u[1][2] * u[2][1],
                        u[1][2] * u[2][0] - u[1][0] * u[2][2],
                        u[1][0] * u[2][1] - u[1][1] * u[2][0]};
        double detU = u[0][0] * cr[0] + u[0][1] * cr[1] + u[0][2] * cr[2];
        double cv[3] = {v[1][1] * v[2][2] - v[1][2] * v[2][1],
                        v[1][2] * v[2][0] - v[1][0] * v[2][2],
                        v[1][0] * v[2][1] - v[1][1] * v[2][0]};
        double detV = v[0][0] * cv[0] + v[0][1] * cv[1] + v[0][2] * cv[2];
        double dsign = detU * detV;
        for (int i = 0; i < 3; i++)
            for (int j = 0; j < 3; j++)
                R[i][j] = v[0][i] * u[0][j] + v[1][i] * u[1][j] + dsign * v[2][i] * u[2][j];
    }
    for (int i = 0; i < 3; i++) {
        double ti = dc[i] - (R[i][0] * sc[0] + R[i][1] * sc[1] + R[i][2] * sc[2]);
        out[9 + i] = (float)ti;
        for (int j = 0; j < 3; j++) out[i * 3 + j] = (float)R[i][j];
    }
}

__global__ __launch_bounds__(256) void pnp_kernel(float* ws, float* out) {
    __shared__ double red[256];
    int t = threadIdx.x;
    double w = (double)ws[WS_WIN + t];
    double x0 = ws[WS_XYZ + t * 3 + 0];
    double x1 = ws[WS_XYZ + t * 3 + 1];
    double x2 = ws[WS_XYZ + t * 3 + 2];
    double z = x2;
    double dd0 = (double)ws[WS_UV + t * 3 + 0] * z;
    double dd1 = (double)ws[WS_UV + t * 3 + 1] * z;
    double dd2 = z;
    auto reduce = [&](double v) -> double {
        red[t] = v; __syncthreads();
        for (int s = 128; s > 0; s >>= 1) {
            if (t < s) red[t] += red[t + s];
            __syncthreads();
        }
        double r = red[0]; __syncthreads();
        return r;
    };
    double wsum = reduce(w);
    double sx0 = reduce(w * x0), sx1 = reduce(w * x1), sx2 = reduce(w * x2);
    double sd0 = reduce(w * dd0), sd1 = reduce(w * dd1), sd2 = reduce(w * dd2);
    double inv = 1.0 / (wsum + 1e-8);
    double sc[3] = {sx0 * inv, sx1 * inv, sx2 * inv};
    double dc[3] = {sd0 * inv, sd1 * inv, sd2 * inv};
    double wn = w * inv;
    double a0 = x0 - sc[0], a1 = x1 - sc[1], a2 = x2 - sc[2];
    double b0 = dd0 - dc[0], b1 = dd1 - dc[1], b2 = dd2 - dc[2];
    double Hm[9];
    Hm[0] = reduce(wn * a0 * b0); Hm[1] = reduce(wn * a0 * b1); Hm[2] = reduce(wn * a0 * b2);
    Hm[3] = reduce(wn * a1 * b0); Hm[4] = reduce(wn * a1 * b1); Hm[5] = reduce(wn * a1 * b2);
    Hm[6] = reduce(wn * a2 * b0); Hm[7] = reduce(wn * a2 * b1); Hm[8] = reduce(wn * a2 * b2);
    if (t == 0) compute_rt(Hm, sc, dc, out);
}

// ---------------- launch ----------------
extern "C" void kernel_launch(void* const* d_in, const int* in_sizes, int n_in,
                              void* d_out, int out_size, void* d_ws, size_t ws_size,
                              hipStream_t stream) {
    float* ws = (float*)d_ws;
    const float* wxyz = (const float*)d_in[0];
    const float* wpts = (const float*)d_in[1];
    const float* RF3  = (const float*)d_in[2];
    const float* RFI  = (const float*)d_in[3];
    const float* lz   = (const float*)d_in[4];
    const float* w2_0 = (const float*)d_in[5];  const float* b2_0 = (const float*)d_in[6];
    const float* w2_1 = (const float*)d_in[7];  const float* b2_1 = (const float*)d_in[8];
    const float* w2_2 = (const float*)d_in[9];  const float* b2_2 = (const float*)d_in[10];
    const float* w3_0 = (const float*)d_in[11]; const float* b3_0 = (const float*)d_in[12];
    const float* w3_1 = (const float*)d_in[13]; const float* b3_1 = (const float*)d_in[14];
    const float* w3_2 = (const float*)d_in[15]; const float* b3_2 = (const float*)d_in[16];
    const float* w1_0 = (const float*)d_in[17]; const float* b1_0 = (const float*)d_in[18];
    const float* w1_1 = (const float*)d_in[19]; const float* b1_1 = (const float*)d_in[20];
    const float* w1_2 = (const float*)d_in[21]; const float* b1_2 = (const float*)d_in[22];
    const float* wm_0 = (const float*)d_in[23]; const float* bm_0 = (const float*)d_in[24];
    const float* wm_1 = (const float*)d_in[25]; const float* bm_1 = (const float*)d_in[26];
    const float* wm_2 = (const float*)d_in[27]; const float* bm_2 = (const float*)d_in[28];
    float* out = (float*)d_out;

    prep_kernel<<<319, 256, 0, stream>>>(ws, wxyz, lz, RF3, RFI, w1_1, w1_2);
    rownorm2_kernel<<<1280, 64, 0, stream>>>(wpts, ws + WS_SN, ws + WS_RF, ws + WS_DN);
    sim_kernel<<<1024, 256, 0, stream>>>(ws + WS_DN, ws + WS_SN, ws + WS_SIM1, ws + WS_RM1);
    colmax_kernel<<<256, 256, 0, stream>>>(ws + WS_SIM1, ws + WS_CM1);
    knn_kernel<<<256, 256, 0, stream>>>(ws);
    mlp2_kernel<<<256, 256, 0, stream>>>(ws, wpts, w2_0, b2_0, w2_1, b2_1, w2_2, b2_2);
    g3_kernel<<<1025, 64, 0, stream>>>(ws, w3_0, b3_0);
    mlp3_kernel<<<256, 256, 0, stream>>>(ws, w3_1, b3_1, w3_2, b3_2);
    rownorm2_kernel<<<1280, 64, 0, stream>>>(ws + WS_PCF, ws + WS_PCN, ws + WS_IMGF, ws + WS_IMGN);
    sim_kernel<<<1024, 256, 0, stream>>>(ws + WS_IMGN, ws + WS_PCN, ws + WS_SIM2, ws + WS_RM2);
    colmax_kernel<<<256, 256, 0, stream>>>(ws + WS_SIM2, ws + WS_CM2);
    base12_kernel<<<1280, 128, 0, stream>>>(ws, wpts, w1_0, b1_0);
    mlp1_kernel<<<dim3(4, 256), 256, 0, stream>>>(ws, w1_0, b1_1, b1_2);
    combinehead_kernel<<<256, 128, 0, stream>>>(ws, wm_0, bm_0, wm_1, bm_1, wm_2, bm_2, out);
    pnp_kernel<<<1, 256, 0, stream>>>(ws, out);
}

// Round 8
// 259.794 us; speedup vs baseline: 2.6441x; 1.0865x over previous
//
#include <hip/hip_runtime.h>
#include <math.h>

// Problem constants
// B=1, N=256, H=32, W=32, M=1024, C_LIDAR=C_RGB=64, K=16, S=3, MLP3=[128,64,64]

typedef _Float16 f16;
typedef __attribute__((ext_vector_type(4))) _Float16 f16x4;
typedef __attribute__((ext_vector_type(8))) _Float16 f16x8;
typedef __attribute__((ext_vector_type(4))) float f32x4;

// ---------------- workspace layout (float offsets) ----------------
constexpr int WS_XYZ  = 0;                  // 256*3
constexpr int WS_RF   = 768;                // 1024*64
constexpr int WS_RFI  = WS_RF   + 65536;    // 1024*3
constexpr int WS_SN   = WS_RFI  + 3072;     // 256*64
constexpr int WS_DN   = WS_SN   + 16384;    // 1024*64
constexpr int WS_SIM1 = WS_DN   + 65536;    // 1024*256 sim[m][n]
constexpr int WS_RM1  = WS_SIM1 + 262144;   // 1024 max over n
constexpr int WS_CM1  = WS_RM1  + 1024;     // 256  max over m
constexpr int WS_PCF  = WS_CM1  + 256;      // 256*64
constexpr int WS_IMGF = WS_PCF  + 16384;    // 1024*64
constexpr int WS_PCN  = WS_IMGF + 65536;    // 256*64
constexpr int WS_IMGN = WS_PCN  + 16384;    // 1024*64
constexpr int WS_SIM2 = WS_IMGN + 65536;    // 1024*256
constexpr int WS_RM2  = WS_SIM2 + 262144;   // 1024
constexpr int WS_CM2  = WS_RM2  + 1024;     // 256
constexpr int WS_B1   = WS_CM2  + 256;      // 256*128
constexpr int WS_B2   = WS_B1   + 32768;    // 1024*128
constexpr int WS_ATT  = WS_B2   + 131072;   // 256*64 (unused, layout keep)
constexpr int WS_UV   = WS_ATT  + 16384;    // 256*3
constexpr int WS_WIN  = WS_UV   + 768;      // 256
constexpr int WS_KNN  = WS_WIN  + 256;      // 256*16 ints
constexpr int WS_PM   = WS_KNN  + 4096;     // 256*4 partial max
constexpr int WS_PS   = WS_PM   + 1024;     // 256*4 partial sum
constexpr int WS_PATT = WS_PS   + 1024;     // 256*4*64 partial att
constexpr int WS_PUV  = WS_PATT + 65536;    // 256*4*3 partial uv
constexpr int WS_W11T = WS_PUV  + 3072;     // 4096 floats = 8192 f16 (w1_1^T [col][k])
constexpr int WS_W12T = WS_W11T + 4096;     // 2048 floats = 4096 f16 (w1_2^T [col][k])
constexpr int WS_G3   = WS_W12T + 2048;     // 1025*64 (MLP3 layer-1 per-pixel)

// ---------------- prep: transposes + f16 weight transposes ----------------
__global__ __launch_bounds__(256) void prep_kernel(float* ws, const float* wxyz,
                                                   const float* lz, const float* RF3,
                                                   const float* RFI, const float* w11,
                                                   const float* w12) {
    int i = blockIdx.x * 256 + threadIdx.x;
    if (i < 768) {
        int n = i / 3;
        ws[WS_XYZ + i] = wxyz[i] * lz[n];
    } else if (i < 768 + 65536) {
        int j = i - 768; int mm = j >> 6, c = j & 63;
        ws[WS_RF + j] = RF3[c * 1024 + mm];
    } else if (i < 768 + 65536 + 3072) {
        int j = i - (768 + 65536); int mm = j / 3, c = j - mm * 3;
        ws[WS_RFI + j] = RFI[c * 1024 + mm];
    } else if (i < 69376 + 8192) {
        int j = i - 69376; int col = j >> 7, k = j & 127;
        ((f16*)(ws + WS_W11T))[col * 128 + k] = (f16)w11[k * 64 + col];
    } else if (i < 69376 + 12288) {
        int j = i - (69376 + 8192); int col = j >> 6, k = j & 63;
        ((f16*)(ws + WS_W12T))[col * 64 + k] = (f16)w12[k * 64 + col];
    }
}

// ---------------- fused double row L2-normalize (64 cols) ----------------
__global__ __launch_bounds__(64) void rownorm2_kernel(const float* sA, float* dA,
                                                      const float* sB, float* dB) {
    int b = blockIdx.x, t = threadIdx.x;
    const float* src; float* dst; int r;
    if (b < 256) { src = sA; dst = dA; r = b; }
    else         { src = sB; dst = dB; r = b - 256; }
    float v = src[r * 64 + t];
    float s = v * v;
    for (int o = 32; o > 0; o >>= 1) s += __shfl_down(s, o);
    s = __shfl(s, 0);
    float nrm = sqrtf(s);
    dst[r * 64 + t] = v / fmaxf(nrm, 1e-12f);
}

// ---------------- sim[m][n] = d[m] . s[n]; rowmax over n ----------------
__global__ __launch_bounds__(256) void sim_kernel(const float* dn, const float* sn,
                                                  float* sim, float* rmax) {
    __shared__ __align__(16) float dv[64];
    __shared__ float red[256];
    int m = blockIdx.x, t = threadIdx.x;
    if (t < 64) dv[t] = dn[m * 64 + t];
    __syncthreads();
    float acc = 0.f;
    const float4* sp = (const float4*)(sn + t * 64);
    const float4* dp = (const float4*)dv;
    for (int i = 0; i < 16; i++) {
        float4 s4 = sp[i], d4 = dp[i];
        acc += s4.x * d4.x + s4.y * d4.y + s4.z * d4.z + s4.w * d4.w;
    }
    sim[m * 256 + t] = acc;
    red[t] = acc; __syncthreads();
    for (int s = 128; s > 0; s >>= 1) {
        if (t < s) red[t] = fmaxf(red[t], red[t + s]);
        __syncthreads();
    }
    if (t == 0) rmax[m] = red[0];
}

// ---------------- colmax over m per n ----------------
__global__ __launch_bounds__(256) void colmax_kernel(const float* sim, float* cmax) {
    __shared__ float red[256];
    int n = blockIdx.x, t = threadIdx.x;
    float mx = -INFINITY;
    for (int m = t; m < 1024; m += 256) mx = fmaxf(mx, sim[m * 256 + n]);
    red[t] = mx; __syncthreads();
    for (int s = 128; s > 0; s >>= 1) {
        if (t < s) red[t] = fmaxf(red[t], red[t + s]);
        __syncthreads();
    }
    if (t == 0) cmax[n] = red[0];
}

// ---------------- 16-NN per point (R2-exact LDS tree version; do NOT replace
// with __shfl_down argmin — that variant miscomputed on gfx950, R3-R5) --------
__global__ __launch_bounds__(256) void knn_kernel(float* ws) {
    const float* xyz = ws + WS_XYZ;
    int* knn = (int*)(ws + WS_KNN);
    __shared__ float px[256], py[256], pz[256], d2[256];
    __shared__ float rv[256];
    __shared__ int   ri[256];
    int n = blockIdx.x, t = threadIdx.x;
    px[t] = xyz[t * 3 + 0]; py[t] = xyz[t * 3 + 1]; pz[t] = xyz[t * 3 + 2];
    __syncthreads();
    float dx = px[t] - px[n], dy = py[t] - py[n], dz = pz[t] - pz[n];
    d2[t] = dx * dx + dy * dy + dz * dz;
    __syncthreads();
    for (int k = 0; k < 16; k++) {
        rv[t] = d2[t]; ri[t] = t;
        __syncthreads();
        for (int s = 128; s > 0; s >>= 1) {
            if (t < s) {
                float v2 = rv[t + s]; int i2 = ri[t + s];
                if (v2 < rv[t] || (v2 == rv[t] && i2 < ri[t])) { rv[t] = v2; ri[t] = i2; }
            }
            __syncthreads();
        }
        if (t == 0) { knn[n * 16 + k] = ri[0]; d2[ri[0]] = INFINITY; }
        __syncthreads();
    }
}

// ---------------- point branch: MLP2 over 16 neighbors -> pc_feats ----------------
__global__ __launch_bounds__(256) void mlp2_kernel(float* ws, const float* wpts,
        const float* w0, const float* b0, const float* w1, const float* b1,
        const float* w2, const float* b2) {
    __shared__ float wA[68 * 64], wB[64 * 64], wC[64 * 64];
    __shared__ float bA[64], bB[64], bC[64];
    __shared__ float x[16 * 68], hA[16 * 68], hB[16 * 68];
    __shared__ int   kn[16];
    __shared__ float wv[16], wts[16];
    int n = blockIdx.x, t = threadIdx.x;
    const float* xyz = ws + WS_XYZ;
    const int* knn = (const int*)(ws + WS_KNN);
    for (int i = t; i < 68 * 64; i += 256) wA[i] = w0[i];
    for (int i = t; i < 64 * 64; i += 256) { wB[i] = w1[i]; wC[i] = w2[i]; }
    if (t < 64) { bA[t] = b0[t]; bB[t] = b1[t]; bC[t] = b2[t]; }
    if (t < 16) kn[t] = knn[n * 16 + t];
    __syncthreads();
    for (int i = t; i < 1024; i += 256) {
        int k = i >> 6, c = i & 63;
        x[k * 68 + c] = wpts[kn[k] * 64 + c];
    }
    if (t < 16) {
        int i = kn[t];
        float dx = xyz[i * 3 + 0] - xyz[n * 3 + 0];
        float dy = xyz[i * 3 + 1] - xyz[n * 3 + 1];
        float dz = xyz[i * 3 + 2] - xyz[n * 3 + 2];
        x[t * 68 + 64] = dx; x[t * 68 + 65] = dy; x[t * 68 + 66] = dz;
        x[t * 68 + 67] = sqrtf(dx * dx + dy * dy + dz * dz);
    }
    __syncthreads();
    for (int o = t; o < 1024; o += 256) {
        int k = o >> 6, j = o & 63; float acc = bA[j];
        for (int i = 0; i < 68; i++) acc += x[k * 68 + i] * wA[i * 64 + j];
        hA[k * 68 + j] = fmaxf(acc, 0.f);
    }
    __syncthreads();
    for (int o = t; o < 1024; o += 256) {
        int k = o >> 6, j = o & 63; float acc = bB[j];
        for (int i = 0; i < 64; i++) acc += hA[k * 68 + i] * wB[i * 64 + j];
        hB[k * 68 + j] = fmaxf(acc, 0.f);
    }
    __syncthreads();
    for (int o = t; o < 1024; o += 256) {
        int k = o >> 6, j = o & 63; float acc = bC[j];
        for (int i = 0; i < 64; i++) acc += hB[k * 68 + i] * wC[i * 64 + j];
        hA[k * 68 + j] = fmaxf(acc, 0.f);
    }
    __syncthreads();
    if (t < 16) {
        float mx = -INFINITY;
        for (int j = 0; j < 64; j++) mx = fmaxf(mx, hA[t * 68 + j]);
        wv[t] = mx;
    }
    __syncthreads();
    if (t < 16) {
        float mx = -INFINITY;
        for (int k = 0; k < 16; k++) mx = fmaxf(mx, wv[k]);
        float sum = 0.f;
        for (int k = 0; k < 16; k++) sum += expf(wv[k] - mx);
        wts[t] = expf(wv[t] - mx) / sum;
    }
    __syncthreads();
    if (t < 64) {
        float acc = 0.f;
        for (int k = 0; k < 16; k++) acc += wts[k] * x[k * 68 + t];
        ws[WS_PCF + n * 64 + t] = acc;
    }
}

// ---------------- MLP3 layer-1 per-pixel GEMV ----------------
__global__ __launch_bounds__(64) void g3_kernel(float* ws, const float* w0, const float* b0) {
    int m = blockIdx.x, j = threadIdx.x;
    float acc = b0[j];
    if (m < 1024) {
        for (int i = 0; i < 3; i++)  acc += ws[WS_RFI + m * 3 + i] * w0[i * 64 + j];
        for (int c = 0; c < 64; c++) acc += ws[WS_RF + m * 64 + c] * w0[(3 + c) * 64 + j];
    }
    ws[WS_G3 + m * 64 + j] = fmaxf(acc, 0.f);
}

// ---------------- image branch: layers 2/3 over gathered G -> img_feats ----------
__global__ __launch_bounds__(256) void mlp3_kernel(float* ws,
        const float* w1, const float* b1, const float* w2, const float* b2) {
    __shared__ float wB[64 * 64], wC[64 * 64];
    __shared__ float bB[64], bC[64];
    __shared__ float x1[36 * 68], h2[36 * 68];
    __shared__ float h3v[36], iw9[36];
    int m0 = blockIdx.x * 4, t = threadIdx.x;
    const float* G = ws + WS_G3;
    const float* rf = ws + WS_RF;
    for (int i = t; i < 4096; i += 256) { wB[i] = w1[i]; wC[i] = w2[i]; }
    if (t < 64) { bB[t] = b1[t]; bC[t] = b2[t]; }
    for (int i = t; i < 36 * 64; i += 256) {
        int row = i >> 6, c = i & 63;
        int mi = row / 9, kk = row - mi * 9;
        int m = m0 + mi; int y = m >> 5, x = m & 31;
        int dy = kk / 3 - 1, dx = kk % 3 - 1;
        int ny = y + dy, nx = x + dx;
        bool val = (ny >= 0 && ny < 32 && nx >= 0 && nx < 32);
        int idx = val ? (ny * 32 + nx) : 1024;
        x1[row * 68 + c] = G[idx * 64 + c];
    }
    __syncthreads();
    for (int o = t; o < 36 * 64; o += 256) {
        int row = o >> 6, c = o & 63; float acc = bB[c];
        for (int i = 0; i < 64; i++) acc += x1[row * 68 + i] * wB[i * 64 + c];
        h2[row * 68 + c] = fmaxf(acc, 0.f);
    }
    __syncthreads();
    for (int o = t; o < 36 * 64; o += 256) {
        int row = o >> 6, c = o & 63; float acc = bC[c];
        for (int i = 0; i < 64; i++) acc += h2[row * 68 + i] * wC[i * 64 + c];
        x1[row * 68 + c] = fmaxf(acc, 0.f);
    }
    __syncthreads();
    if (t < 36) {
        float mx = -INFINITY;
        for (int c = 0; c < 64; c++) mx = fmaxf(mx, x1[t * 68 + c]);
        h3v[t] = mx;
    }
    __syncthreads();
    if (t < 36) {
        int mi = t / 9;
        float mx = -INFINITY;
        for (int k = 0; k < 9; k++) mx = fmaxf(mx, h3v[mi * 9 + k]);
        float sum = 0.f;
        for (int k = 0; k < 9; k++) sum += expf(h3v[mi * 9 + k] - mx);
        iw9[t] = expf(h3v[t] - mx) / sum;
    }
    __syncthreads();
    {
        int mi = t >> 6, c = t & 63;
        int m = m0 + mi; int y = m >> 5, x = m & 31;
        float acc = 0.f;
        for (int kk = 0; kk < 9; kk++) {
            int dy = kk / 3 - 1, dx = kk % 3 - 1;
            int ny = y + dy, nx = x + dx;
            bool val = (ny >= 0 && ny < 32 && nx >= 0 && nx < 32);
            if (val) acc += iw9[mi * 9 + kk] * rf[(ny * 32 + nx) * 64 + c];
        }
        ws[WS_IMGF + m * 64 + c] = acc;
    }
}

// ---------------- fused MLP1 layer-1 decomposition (base1 + base2) ----------------
__global__ __launch_bounds__(128) void base12_kernel(float* ws, const float* wpts,
                                                     const float* w10, const float* b10) {
    int b = blockIdx.x, j = threadIdx.x;
    if (b < 256) {
        int n = b;
        float acc = b10[j];
        for (int i = 0; i < 3; i++)  acc += ws[WS_XYZ + n * 3 + i] * w10[i * 128 + j];
        for (int c = 0; c < 64; c++) acc += wpts[n * 64 + c] * w10[(6 + c) * 128 + j];
        ws[WS_B1 + n * 128 + j] = acc;
    } else {
        int m = b - 256;
        float acc = 0.f;
        for (int i = 0; i < 3; i++)  acc += ws[WS_RFI + m * 3 + i] * w10[(3 + i) * 128 + j];
        for (int c = 0; c < 64; c++) acc += ws[WS_RF + m * 64 + c] * w10[(70 + c) * 128 + j];
        ws[WS_B2 + m * 128 + j] = acc;
    }
}

// ---------------- main fused MLP1 v3: 64-row chunks, register epilogue ----------
// grid (4, 256): blockIdx.x = m-segment (256 m), blockIdx.y = n. 4 waves/block;
// wave w owns output cols [w*16, w*16+16); B-fragments in registers.
// All cross-lane ops are __shfl_xor butterflies (no OOR-lane hazard).
__global__ __launch_bounds__(256) void mlp1_kernel(float* ws, const float* w10,
        const float* b11, const float* b12) {
    __shared__ __align__(16) f16 H1h[64 * 136];   // [row][k]
    __shared__ __align__(16) f16 H2h[64 * 72];    // [row][k]
    __shared__ float base1n[128];
    __shared__ float simw[4 * 128];
    __shared__ float simfb[2][64 * 4];
    __shared__ float rfib[2][64 * 3];
    __shared__ float rmPart[4][64];
    __shared__ float rm[64], ew[64];
    __shared__ float tmaxS;
    int n = blockIdx.y, seg = blockIdx.x, t = threadIdx.x;
    int wave = t >> 6, lane = t & 63, q = lane >> 4, l16 = lane & 15;
    int col = wave * 16 + l16;
    const float* sim1 = ws + WS_SIM1;  const float* rm1g = ws + WS_RM1;
    const float* sim2 = ws + WS_SIM2;  const float* rm2g = ws + WS_RM2;
    const float* base2 = ws + WS_B2;   const float* rfig = ws + WS_RFI;
    const f16* w11t = (const f16*)(ws + WS_W11T);
    const f16* w12t = (const f16*)(ws + WS_W12T);
    float cm1 = ws[WS_CM1 + n], cm2 = ws[WS_CM2 + n];
    if (t < 128) base1n[t] = ws[WS_B1 + n * 128 + t];
    for (int i = t; i < 512; i += 256) simw[i] = w10[134 * 128 + i];
    f16x8 B2f[4], B3f[2];
    for (int s = 0; s < 4; s++) B2f[s] = *(const f16x8*)&w11t[col * 128 + s * 32 + q * 8];
    for (int s = 0; s < 2; s++) B3f[s] = *(const f16x8*)&w12t[col * 64 + s * 32 + q * 8];
    float bias2 = b11[col], bias3 = b12[col];
    float attAcc = 0.f, uvAcc = 0.f;       // attAcc valid in lanes lane<16; uvAcc in t<3
    float Mv = -INFINITY, Sv = 0.f;
    int mBeg = seg * 256;
    // prologue stage (chunk 0 -> buffer 0)
    if (t < 64) {
        int m = mBeg + t;
        float s1 = sim1[m * 256 + n], r1 = rm1g[m];
        float s2 = sim2[m * 256 + n], r2 = rm2g[m];
        simfb[0][t * 4 + 0] = s1 / (cm1 + 1e-6f);
        simfb[0][t * 4 + 1] = s1 / (r1 + 1e-10f);
        simfb[0][t * 4 + 2] = s2 / (cm2 + 1e-6f);
        simfb[0][t * 4 + 3] = s2 / (r2 + 1e-10f);
    } else if (t < 256) {
        int i = t - 64;
        if (i < 192) rfib[0][i] = rfig[mBeg * 3 + i];
    }
    __syncthreads();
    for (int c4 = 0; c4 < 4; c4++) {
        int par = c4 & 1;
        int m0 = mBeg + c4 * 64;
        // ---- layer 1: 64 rows x 128 k, vectorized x4 over k ----
        for (int idx = t; idx < 2048; idx += 256) {
            int row = idx >> 5, k4 = (idx & 31) * 4;
            int m = m0 + row;
            const float* sf = &simfb[par][row * 4];
            float s0 = sf[0], s1 = sf[1], s2 = sf[2], s3 = sf[3];
            float4 bs = *(const float4*)&base2[m * 128 + k4];
            float4 b1v = *(const float4*)&base1n[k4];
            float4 w0v = *(const float4*)&simw[k4];
            float4 w1v = *(const float4*)&simw[128 + k4];
            float4 w2v = *(const float4*)&simw[256 + k4];
            float4 w3v = *(const float4*)&simw[384 + k4];
            float v0 = b1v.x + bs.x + s0 * w0v.x + s1 * w1v.x + s2 * w2v.x + s3 * w3v.x;
            float v1 = b1v.y + bs.y + s0 * w0v.y + s1 * w1v.y + s2 * w2v.y + s3 * w3v.y;
            float v2 = b1v.z + bs.z + s0 * w0v.z + s1 * w1v.z + s2 * w2v.z + s3 * w3v.z;
            float v3 = b1v.w + bs.w + s0 * w0v.w + s1 * w1v.w + s2 * w2v.w + s3 * w3v.w;
            *(f16x4*)&H1h[row * 136 + k4] = (f16x4){
                (f16)fmaxf(v0, 0.f), (f16)fmaxf(v1, 0.f),
                (f16)fmaxf(v2, 0.f), (f16)fmaxf(v3, 0.f)};
        }
        __syncthreads();                               // B1: H1h ready
        // ---- stage next chunk into the other buffer (overlaps layer 2) ----
        if (c4 < 3) {
            int nm0 = m0 + 64, npar = 1 - par;
            if (t < 64) {
                int m = nm0 + t;
                float s1 = sim1[m * 256 + n], r1 = rm1g[m];
                float s2 = sim2[m * 256 + n], r2 = rm2g[m];
                simfb[npar][t * 4 + 0] = s1 / (cm1 + 1e-6f);
                simfb[npar][t * 4 + 1] = s1 / (r1 + 1e-10f);
                simfb[npar][t * 4 + 2] = s2 / (cm2 + 1e-6f);
                simfb[npar][t * 4 + 3] = s2 / (r2 + 1e-10f);
            } else {
                int i = t - 64;
                if (i < 192) rfib[npar][i] = rfig[nm0 * 3 + i];
            }
        }
        // ---- layer 2: 4 row-tiles x wave's 16 cols (MFMA) ----
        f32x4 a[4];
        for (int tl = 0; tl < 4; tl++) a[tl] = (f32x4){bias2, bias2, bias2, bias2};
        for (int s = 0; s < 4; s++)
            for (int tl = 0; tl < 4; tl++) {
                f16x8 f = *(const f16x8*)&H1h[(tl * 16 + l16) * 136 + s * 32 + q * 8];
                a[tl] = __builtin_amdgcn_mfma_f32_16x16x32_f16(f, B2f[s], a[tl], 0, 0, 0);
            }
        __syncthreads();                               // B2: H1h reads done
        for (int tl = 0; tl < 4; tl++)
            for (int r = 0; r < 4; r++)
                H2h[(tl * 16 + q * 4 + r) * 72 + col] = (f16)fmaxf(a[tl][r], 0.f);
        __syncthreads();                               // B3: H2h ready
        // ---- layer 3 (MFMA, output stays in registers) ----
        f32x4 c3[4];
        for (int tl = 0; tl < 4; tl++) c3[tl] = (f32x4){bias3, bias3, bias3, bias3};
        for (int s = 0; s < 2; s++)
            for (int tl = 0; tl < 4; tl++) {
                f16x8 f = *(const f16x8*)&H2h[(tl * 16 + l16) * 72 + s * 32 + q * 8];
                c3[tl] = __builtin_amdgcn_mfma_f32_16x16x32_f16(f, B3f[s], c3[tl], 0, 0, 0);
            }
        for (int tl = 0; tl < 4; tl++)
            for (int r = 0; r < 4; r++)
                c3[tl][r] = fmaxf(c3[tl][r], 0.f);
        // ---- row-max via in-wave xor shuffles (within 16-lane groups) ----
        for (int tl = 0; tl < 4; tl++)
            for (int r = 0; r < 4; r++) {
                float v = c3[tl][r];
                v = fmaxf(v, __shfl_xor(v, 1));
                v = fmaxf(v, __shfl_xor(v, 2));
                v = fmaxf(v, __shfl_xor(v, 4));
                v = fmaxf(v, __shfl_xor(v, 8));
                if (l16 == 0) rmPart[wave][tl * 16 + q * 4 + r] = v;
            }
        __syncthreads();                               // B4: rmPart ready
        float rmv = 0.f;
        if (t < 64) {
            rmv = fmaxf(fmaxf(rmPart[0][t], rmPart[1][t]),
                        fmaxf(rmPart[2][t], rmPart[3][t]));
            rm[t] = rmv;
        }
        if (wave == 0) {
            float v = rmv;
            for (int off = 32; off > 0; off >>= 1) v = fmaxf(v, __shfl_xor(v, off));
            if (lane == 0) tmaxS = v;
        }
        __syncthreads();                               // B5: rm/tmax ready
        float newM = fmaxf(Mv, tmaxS);
        float rescale = __expf(Mv - newM);
        float ewv = 0.f;
        if (t < 64) { ewv = __expf(rmv - newM); ew[t] = ewv; }
        Mv = newM;
        if (wave == 0) {                               // Sv update from registers
            float s = ewv;
            for (int off = 32; off > 0; off >>= 1) s += __shfl_xor(s, off);
            if (lane == 0) Sv = Sv * rescale + s;
        }
        __syncthreads();                               // B6: ew ready
        // ---- att: per-lane partial over its 16 rows, quad-reduce ----
        {
            float ap = 0.f;
            for (int tl = 0; tl < 4; tl++)
                for (int r = 0; r < 4; r++)
                    ap += ew[tl * 16 + q * 4 + r] * c3[tl][r];
            ap += __shfl_xor(ap, 16);
            ap += __shfl_xor(ap, 32);
            if (lane < 16) attAcc = attAcc * rescale + ap;
        }
        if (t < 3) {
            float acc = 0.f;
            for (int r = 0; r < 64; r++) acc += ew[r] * rfib[par][r * 3 + t];
            uvAcc = uvAcc * rescale + acc;
        }
    }
    int p = n * 4 + seg;
    if (t == 0) { ws[WS_PM + p] = Mv; ws[WS_PS + p] = Sv; }
    if (lane < 16) ws[WS_PATT + p * 64 + wave * 16 + lane] = attAcc;
    if (t < 3) ws[WS_PUV + p * 3 + t] = uvAcc;
}

// ---------------- fused combine + head MLP -> weights (d_out), w_in, uv ------------
__global__ __launch_bounds__(128) void combinehead_kernel(float* ws,
        const float* wm0, const float* bm0, const float* wm1, const float* bm1,
        const float* wm2, const float* bm2, float* out) {
    __shared__ float av[64], ha[64], hb[128], lg[2];
    int n = blockIdx.x, t = threadIdx.x;
    float pm[4], e[4];
    float M = -INFINITY;
    for (int s = 0; s < 4; s++) { pm[s] = ws[WS_PM + n * 4 + s]; M = fmaxf(M, pm[s]); }
    float S = 0.f;
    for (int s = 0; s < 4; s++) { e[s] = expf(pm[s] - M); S += ws[WS_PS + n * 4 + s] * e[s]; }
    if (t < 64) {
        float acc = 0.f;
        for (int s = 0; s < 4; s++) acc += ws[WS_PATT + (n * 4 + s) * 64 + t] * e[s];
        av[t] = acc / S;
    } else if (t < 67) {
        int c = t - 64; float acc = 0.f;
        for (int s = 0; s < 4; s++) acc += ws[WS_PUV + (n * 4 + s) * 3 + c] * e[s];
        ws[WS_UV + n * 3 + c] = acc / S;
    }
    __syncthreads();
    if (t < 64) {
        float acc = bm0[t];
        for (int i = 0; i < 64; i++) acc += av[i] * wm0[i * 64 + t];
        ha[t] = fmaxf(acc, 0.f);
    }
    __syncthreads();
    {
        float acc = bm1[t];
        for (int i = 0; i < 64; i++) acc += ha[i] * wm1[i * 128 + t];
        hb[t] = fmaxf(acc, 0.f);
    }
    __syncthreads();
    if (t < 2) {
        float acc = bm2[t];
        for (int i = 0; i < 128; i++) acc += hb[i] * wm2[i * 2 + t];
        lg[t] = acc;
    }
    __syncthreads();
    if (t == 0) {
        float l0 = lg[0], l1 = lg[1];
        float mx = fmaxf(l0, l1);
        float e0 = expf(l0 - mx), e1 = expf(l1 - mx);
        float s = e0 + e1;
        out[12 + n * 2 + 0] = e0 / s;
        out[12 + n * 2 + 1] = e1 / s;
        ws[WS_WIN + n] = (e1 > e0) ? 1.f : 0.f;
    }
}

// ---------------- weighted PnP (Kabsch with 3x3 SVD, double) ----------------
__device__ void compute_rt(const double Hm[9], const double sc[3], const double dc[3],
                           float* out) {
    double Hd[3][3] = {{Hm[0], Hm[1], Hm[2]}, {Hm[3], Hm[4], Hm[5]}, {Hm[6], Hm[7], Hm[8]}};
    double A[3][3], V[3][3] = {{1, 0, 0}, {0, 1, 0}, {0, 0, 1}};
    for (int i = 0; i < 3; i++)
        for (int j = 0; j < 3; j++) {
            double s = 0;
            for (int k = 0; k < 3; k++) s += Hd[k][i] * Hd[k][j];
            A[i][j] = s;
        }
    for (int sweep = 0; sweep < 50; sweep++) {
        double off = fabs(A[0][1]) + fabs(A[0][2]) + fabs(A[1][2]);
        if (off < 1e-28) break;
        const int PQ[3][2] = {{0, 1}, {0, 2}, {1, 2}};
        for (int pp = 0; pp < 3; pp++) {
            int p = PQ[pp][0], q = PQ[pp][1];
            double apq = A[p][q];
            if (fabs(apq) < 1e-300) continue;
            double tau = (A[q][q] - A[p][p]) / (2.0 * apq);
            double tt = (tau >= 0.0 ? 1.0 : -1.0) / (fabs(tau) + sqrt(1.0 + tau * tau));
            double c = 1.0 / sqrt(1.0 + tt * tt), s = tt * c;
            for (int k = 0; k < 3; k++) {
                double akp = A[k][p], akq = A[k][q];
                A[k][p] = c * akp - s * akq; A[k][q] = s * akp + c * akq;
            }
            for (int k = 0; k < 3; k++) {
                double apk = A[p][k], aqk = A[q][k];
                A[p][k] = c * apk - s * aqk; A[q][k] = s * apk + c * aqk;
            }
            for (int k = 0; k < 3; k++) {
                double vkp = V[k][p], vkq = V[k][q];
                V[k][p] = c * vkp - s * vkq; V[k][q] = s * vkp + c * vkq;
            }
        }
    }
    double lam[3] = {A[0][0], A[1][1], A[2][2]};
    int o0 = 0, o1 = 1, o2 = 2;
    if (lam[o0] < lam[o1]) { int tp = o0; o0 = o1; o1 = tp; }
    if (lam[o0] < lam[o2]) { int tp = o0; o0 = o2; o2 = tp; }
    if (lam[o1] < lam[o2]) { int tp = o1; o1 = o2; o2 = tp; }
    int ord[3] = {o0, o1, o2};
    double v[3][3], u[3][3], R[3][3];
    for (int k = 0; k < 3; k++)
        for (int i = 0; i < 3; i++) v[k][i] = V[i][ord[k]];
    double sv0 = sqrt(fmax(lam[o0], 0.0));
    if (!(sv0 > 1e-150)) {
        for (int i = 0; i < 3; i++)
            for (int j = 0; j < 3; j++) R[i][j] = (i == j) ? 1.0 : 0.0;
    } else {
        double nn[3];
        for (int k = 0; k < 3; k++) {
            for (int i = 0; i < 3; i++)
                u[k][i] = Hd[i][0] * v[k][0] + Hd[i][1] * v[k][1] + Hd[i][2] * v[k][2];
            nn[k] = sqrt(u[k][0] * u[k][0] + u[k][1] * u[k][1] + u[k][2] * u[k][2]);
        }
        for (int i = 0; i < 3; i++) u[0][i] /= nn[0];
        if (nn[1] > 1e-12 * nn[0]) {
            for (int i = 0; i < 3; i++) u[1][i] /= nn[1];
        } else {
            int e = (fabs(u[0][0]) <= fabs(u[0][1]) && fabs(u[0][0]) <= fabs(u[0][2])) ? 0
                    : ((fabs(u[0][1]) <= fabs(u[0][2])) ? 1 : 2);
            double ev[3] = {0, 0, 0}; ev[e] = 1.0;
            double d0 = ev[0] * u[0][0] + ev[1] * u[0][1] + ev[2] * u[0][2];
            double w1v[3], wn2 = 0;
            for (int i = 0; i < 3; i++) { w1v[i] = ev[i] - d0 * u[0][i]; wn2 += w1v[i] * w1v[i]; }
            wn2 = sqrt(wn2);
            for (int i = 0; i < 3; i++) u[1][i] = w1v[i] / wn2;
        }
        if (nn[2] > 1e-10 * nn[0]) {
            for (int i = 0; i < 3; i++) u[2][i] /= nn[2];
        } else {
            u[2][0] = u[0][1] * u[1][2] - u[0][2] * u[1][1];
            u[2][1] = u[0][2] * u[1][0] - u[0][0] * u[1][2];
            u[2][2] = u[0][0] * u[1][1] - u[0][1] * u[1][0];
        }
        double cr[3] = {u[1][1] * u[2][2] - u[1][2] * u[2][1],
                        u[1][2] * u[2][0] - u[1][0] * u[2][2],
                        u[1][0] * u[2][1] - u[1][1] * u[2][0]};
        double detU = u[0][0] * cr[0] + u[0][1] * cr[1] + u[0][2] * cr[2];
        double cv[3] = {v[1][1] * v[2][2] - v[1][2] * v[2][1],
                        v[1][2] * v[2][0] - v[1][0] * v[2][2],
                        v[1][0] * v[2][1] - v[1][1] * v[2][0]};
        double detV = v[0][0] * cv[0] + v[0][1] * cv[1] + v[0][2] * cv[2];
        double dsign = detU * detV;
        for (int i = 0; i < 3; i++)
            for (int j = 0; j < 3; j++)
                R[i][j] = v[0][i] * u[0][j] + v[1][i] * u[1][j] + dsign * v[2][i] * u[2][j];
    }
    for (int i = 0; i < 3; i++) {
        double ti = dc[i] - (R[i][0] * sc[0] + R[i][1] * sc[1] + R[i][2] * sc[2]);
        out[9 + i] = (float)ti;
        for (int j = 0; j < 3; j++) out[i * 3 + j] = (float)R[i][j];
    }
}

__global__ __launch_bounds__(256) void pnp_kernel(float* ws, float* out) {
    __shared__ double red[256];
    int t = threadIdx.x;
    double w = (double)ws[WS_WIN + t];
    double x0 = ws[WS_XYZ + t * 3 + 0];
    double x1 = ws[WS_XYZ + t * 3 + 1];
    double x2 = ws[WS_XYZ + t * 3 + 2];
    double z = x2;
    double dd0 = (double)ws[WS_UV + t * 3 + 0] * z;
    double dd1 = (double)ws[WS_UV + t * 3 + 1] * z;
    double dd2 = z;
    auto reduce = [&](double v) -> double {
        red[t] = v; __syncthreads();
        for (int s = 128; s > 0; s >>= 1) {
            if (t < s) red[t] += red[t + s];
            __syncthreads();
        }
        double r = red[0]; __syncthreads();
        return r;
    };
    double wsum = reduce(w);
    double sx0 = reduce(w * x0), sx1 = reduce(w * x1), sx2 = reduce(w * x2);
    double sd0 = reduce(w * dd0), sd1 = reduce(w * dd1), sd2 = reduce(w * dd2);
    double inv = 1.0 / (wsum + 1e-8);
    double sc[3] = {sx0 * inv, sx1 * inv, sx2 * inv};
    double dc[3] = {sd0 * inv, sd1 * inv, sd2 * inv};
    double wn = w * inv;
    double a0 = x0 - sc[0], a1 = x1 - sc[1], a2 = x2 - sc[2];
    double b0 = dd0 - dc[0], b1 = dd1 - dc[1], b2 = dd2 - dc[2];
    double Hm[9];
    Hm[0] = reduce(wn * a0 * b0); Hm[1] = reduce(wn * a0 * b1); Hm[2] = reduce(wn * a0 * b2);
    Hm[3] = reduce(wn * a1 * b0); Hm[4] = reduce(wn * a1 * b1); Hm[5] = reduce(wn * a1 * b2);
    Hm[6] = reduce(wn * a2 * b0); Hm[7] = reduce(wn * a2 * b1); Hm[8] = reduce(wn * a2 * b2);
    if (t == 0) compute_rt(Hm, sc, dc, out);
}

// ---------------- launch ----------------
extern "C" void kernel_launch(void* const* d_in, const int* in_sizes, int n_in,
                              void* d_out, int out_size, void* d_ws, size_t ws_size,
                              hipStream_t stream) {
    float* ws = (float*)d_ws;
    const float* wxyz = (const float*)d_in[0];
    const float* wpts = (const float*)d_in[1];
    const float* RF3  = (const float*)d_in[2];
    const float* RFI  = (const float*)d_in[3];
    const float* lz   = (const float*)d_in[4];
    const float* w2_0 = (const float*)d_in[5];  const float* b2_0 = (const float*)d_in[6];
    const float* w2_1 = (const float*)d_in[7];  const float* b2_1 = (const float*)d_in[8];
    const float* w2_2 = (const float*)d_in[9];  const float* b2_2 = (const float*)d_in[10];
    const float* w3_0 = (const float*)d_in[11]; const float* b3_0 = (const float*)d_in[12];
    const float* w3_1 = (const float*)d_in[13]; const float* b3_1 = (const float*)d_in[14];
    const float* w3_2 = (const float*)d_in[15]; const float* b3_2 = (const float*)d_in[16];
    const float* w1_0 = (const float*)d_in[17]; const float* b1_0 = (const float*)d_in[18];
    const float* w1_1 = (const float*)d_in[19]; const float* b1_1 = (const float*)d_in[20];
    const float* w1_2 = (const float*)d_in[21]; const float* b1_2 = (const float*)d_in[22];
    const float* wm_0 = (const float*)d_in[23]; const float* bm_0 = (const float*)d_in[24];
    const float* wm_1 = (const float*)d_in[25]; const float* bm_1 = (const float*)d_in[26];
    const float* wm_2 = (const float*)d_in[27]; const float* bm_2 = (const float*)d_in[28];
    float* out = (float*)d_out;

    prep_kernel<<<319, 256, 0, stream>>>(ws, wxyz, lz, RF3, RFI, w1_1, w1_2);
    rownorm2_kernel<<<1280, 64, 0, stream>>>(wpts, ws + WS_SN, ws + WS_RF, ws + WS_DN);
    sim_kernel<<<1024, 256, 0, stream>>>(ws + WS_DN, ws + WS_SN, ws + WS_SIM1, ws + WS_RM1);
    colmax_kernel<<<256, 256, 0, stream>>>(ws + WS_SIM1, ws + WS_CM1);
    knn_kernel<<<256, 256, 0, stream>>>(ws);
    mlp2_kernel<<<256, 256, 0, stream>>>(ws, wpts, w2_0, b2_0, w2_1, b2_1, w2_2, b2_2);
    g3_kernel<<<1025, 64, 0, stream>>>(ws, w3_0, b3_0);
    mlp3_kernel<<<256, 256, 0, stream>>>(ws, w3_1, b3_1, w3_2, b3_2);
    rownorm2_kernel<<<1280, 64, 0, stream>>>(ws + WS_PCF, ws + WS_PCN, ws + WS_IMGF, ws + WS_IMGN);
    sim_kernel<<<1024, 256, 0, stream>>>(ws + WS_IMGN, ws + WS_PCN, ws + WS_SIM2, ws + WS_RM2);
    colmax_kernel<<<256, 256, 0, stream>>>(ws + WS_SIM2, ws + WS_CM2);
    base12_kernel<<<1280, 128, 0, stream>>>(ws, wpts, w1_0, b1_0);
    mlp1_kernel<<<dim3(4, 256), 256, 0, stream>>>(ws, w1_0, b1_1, b1_2);
    combinehead_kernel<<<256, 128, 0, stream>>>(ws, wm_0, bm_0, wm_1, bm_1, wm_2, bm_2, out);
    pnp_kernel<<<1, 256, 0, stream>>>(ws, out);
}